// Round 17
// baseline (4990.465 us; speedup 1.0000x reference)
//
#include <hip/hip_runtime.h>
#include <hip/hip_bf16.h>

// ---------- types ----------
typedef __attribute__((ext_vector_type(8))) short  s16x8;
typedef __attribute__((ext_vector_type(4))) float  f32x4;
typedef __attribute__((ext_vector_type(4))) unsigned short u16x4;
typedef __attribute__((ext_vector_type(4))) unsigned int   u32x4;

#define B_  64
#define T_  1024
#define I_  512
#define H_  1024
#define O_  512
#define MT_ 65536   // B_*T_

// scan decomposition: 8 row-groups (8 rows, rg = blockIdx&7 -> one XCD under
// round-robin dispatch) x 16 col-slices; 128 blocks. Waves are FULL-K (no reduce).
#define RG_   8
#define CS_   16

// ---------- helpers ----------
__device__ __forceinline__ unsigned short f2bf(float f) {
    unsigned u = __builtin_bit_cast(unsigned, f);
    u += 0x7FFFu + ((u >> 16) & 1u);
    return (unsigned short)(u >> 16);
}
__device__ __forceinline__ float bf2f(unsigned short h) {
    return __builtin_bit_cast(float, ((unsigned)h) << 16);
}
__device__ __forceinline__ void store_out(float* p, float v) { *p = v; }
__device__ __forceinline__ void store_out(unsigned short* p, float v) { *p = f2bf(v); }
__device__ __forceinline__ void store_nt(float* p, float v) {
    asm volatile("global_store_dword %0, %1, off nt" :: "v"(p), "v"(v) : "memory");
}
__device__ __forceinline__ void store_nt(unsigned short* p, float v) {
    unsigned short h = f2bf(v);
    asm volatile("global_store_short %0, %1, off nt" :: "v"(p), "v"(h) : "memory");
}
__device__ __forceinline__ float to_f32(float v) { return v; }
__device__ __forceinline__ float to_f32(unsigned short v) { return bf2f(v); }

template<typename T> struct pre4;
template<> struct pre4<float>          { using t = f32x4; };
template<> struct pre4<unsigned short> { using t = u16x4; };

__device__ __forceinline__ f32x4 pre_ld(const float* p) {
    f32x4 d; asm volatile("global_load_dwordx4 %0, %1, off nt" : "=v"(d) : "v"(p)); return d;
}
__device__ __forceinline__ u16x4 pre_ld(const unsigned short* p) {
    u16x4 d; asm volatile("global_load_dwordx2 %0, %1, off nt" : "=v"(d) : "v"(p)); return d;
}

#define GL2LDS16(gp, lp) __builtin_amdgcn_global_load_lds( \
    (const __attribute__((address_space(1))) void*)(gp),   \
    (__attribute__((address_space(3))) void*)(lp), 16, 0, 0)

// ---------- conversion kernels ----------
__global__ void cvt_x(const float* __restrict__ src, unsigned short* __restrict__ dst, int n) {
    int stride = gridDim.x * blockDim.x * 4;
    for (int i = (blockIdx.x * blockDim.x + threadIdx.x) * 4; i < n; i += stride) {
        const float4 v = *(const float4*)(src + i);
        u16x4 o;
        o.x = f2bf(v.x); o.y = f2bf(v.y); o.z = f2bf(v.z); o.w = f2bf(v.w);
        *(u16x4*)(dst + i) = o;
    }
}

// dst[c][r] = bf16(src[row_off + r][c]);  src region [SR,SC] row-major -> dst [SC,SR]
__global__ void cvt_t(const float* __restrict__ src, unsigned short* __restrict__ dst,
                      int SR, int SC, int row_off) {
    __shared__ unsigned short tile[32][33];
    int c0 = blockIdx.x * 32, r0 = blockIdx.y * 32;
    int tx = threadIdx.x, ty = threadIdx.y;
    #pragma unroll
    for (int i = 0; i < 32; i += 8)
        tile[ty + i][tx] = f2bf(src[(size_t)(row_off + r0 + ty + i) * SC + c0 + tx]);
    __syncthreads();
    #pragma unroll
    for (int i = 0; i < 32; i += 8)
        dst[(size_t)(c0 + ty + i) * SR + r0 + tx] = tile[tx][ty + i];
}

// unscramble exchange layout (slot 0) -> row-major bf16 h_T.
__global__ void strip_h(const unsigned* __restrict__ src, unsigned short* __restrict__ dst) {
    int idx = blockIdx.x * blockDim.x + threadIdx.x;   // 16384 chunks
    u32x4 v = *(const u32x4*)(src + idx * 4);
    int rg = idx >> 11, c2 = idx & 2047;
    int q = c2 >> 9, c3 = c2 & 511;
    int j = c3 >> 6, c = c3 & 63;
    int p = c >> 5, a = (c >> 3) & 3, row = c & 7;
    int grow = rg * 8 + row;
    int col = q * 256 + j * 32 + a * 8 + p * 4;
    u16x4 o;
    o.x = (unsigned short)(v.x >> 16); o.y = (unsigned short)(v.y >> 16);
    o.z = (unsigned short)(v.z >> 16); o.w = (unsigned short)(v.w >> 16);
    *(u16x4*)(dst + (size_t)grow * H_ + col) = o;
}

// ---------- generic bf16 MFMA GEMM: C[M,N] = act(A[M,K] @ BT[N,K]^T + bias) ----------
template<typename OutT, bool LRELU, bool SCATTER>
__global__ __launch_bounds__(256)
void gemm_bf16(const unsigned short* __restrict__ A,
               const unsigned short* __restrict__ BT,
               const float* __restrict__ bias,
               OutT* __restrict__ C, int M, int K, int N)
{
    __shared__ unsigned short As[4096]; // [128][32]
    __shared__ unsigned short Bs[4096]; // [128][32]
    const int tid = threadIdx.x, lane = tid & 63, wid = tid >> 6;
    const int wr = wid >> 1, wc = wid & 1;
    const int m0 = blockIdx.x * 128, n0 = blockIdx.y * 128;

    f32x4 acc[4][4] = {};

    const int c = wid * 2;
    const int srow = lane >> 2;
    const int scol = (lane & 3) * 8;
    const unsigned short* Ag0 = A  + (size_t)(m0 + c * 16 + srow) * K + scol;
    const unsigned short* Ag1 = A  + (size_t)(m0 + c * 16 + 16 + srow) * K + scol;
    const unsigned short* Bg0 = BT + (size_t)(n0 + c * 16 + srow) * K + scol;
    const unsigned short* Bg1 = BT + (size_t)(n0 + c * 16 + 16 + srow) * K + scol;

    for (int k0 = 0; k0 < K; k0 += 32) {
        __syncthreads();
        GL2LDS16(Ag0 + k0, As + c * 512);
        GL2LDS16(Ag1 + k0, As + (c + 1) * 512);
        GL2LDS16(Bg0 + k0, Bs + c * 512);
        GL2LDS16(Bg1 + k0, Bs + (c + 1) * 512);
        __syncthreads();

        s16x8 af[4], bfr[4];
        #pragma unroll
        for (int i = 0; i < 4; i++)
            af[i] = *(const s16x8*)(As + (wr * 64 + i * 16 + (lane & 15)) * 32 + (lane >> 4) * 8);
        #pragma unroll
        for (int j = 0; j < 4; j++)
            bfr[j] = *(const s16x8*)(Bs + (wc * 64 + j * 16 + (lane & 15)) * 32 + (lane >> 4) * 8);
        #pragma unroll
        for (int i = 0; i < 4; i++)
            #pragma unroll
            for (int j = 0; j < 4; j++)
                acc[i][j] = __builtin_amdgcn_mfma_f32_16x16x32_bf16(af[i], bfr[j], acc[i][j], 0, 0, 0);
    }

    #pragma unroll
    for (int j = 0; j < 4; j++) {
        const int n = n0 + wc * 64 + j * 16 + (lane & 15);
        const float bv = bias[n];
        #pragma unroll
        for (int i = 0; i < 4; i++) {
            #pragma unroll
            for (int r = 0; r < 4; r++) {
                const int m = m0 + wr * 64 + i * 16 + (lane >> 4) * 4 + r;
                if (m < M) {
                    float v = acc[i][j][r] + bv;
                    if (LRELU) v = v >= 0.f ? v : 0.01f * v;
                    if (SCATTER) {
                        size_t row = (size_t)((m & (T_ - 1)) * B_ + (m >> 10));
                        store_nt(&C[row * N + n], v);
                    } else {
                        store_out(&C[(size_t)m * N + n], v);
                    }
                }
            }
        }
    }
}

// ---------- scan v17: barrier-free full-K waves, 2-deep quarter pipeline ----------
// = r16 design; compile fix: global_load offset imm is 13-bit SIGNED (<=4095),
// so each 8KB quarter uses TWO base pointers (BASE, BASE+4096), offsets 0..3584.

#define TAGLD2(d, BASE, OFFSTR, SC) asm volatile( \
    "global_load_dwordx4 %0, %1, off offset:" OFFSTR " " SC \
    : "=v"(d) : "v"(BASE))

#define POLLQ(TV, BASE, BASEH, SC) do { \
    TAGLD2(TV[0],  BASE,  "0",   SC); TAGLD2(TV[1],  BASE,  "512",  SC); \
    TAGLD2(TV[2],  BASE,  "1024",SC); TAGLD2(TV[3],  BASE,  "1536", SC); \
    TAGLD2(TV[4],  BASE,  "2048",SC); TAGLD2(TV[5],  BASE,  "2560", SC); \
    TAGLD2(TV[6],  BASE,  "3072",SC); TAGLD2(TV[7],  BASE,  "3584", SC); \
    TAGLD2(TV[8],  BASEH, "0",   SC); TAGLD2(TV[9],  BASEH, "512",  SC); \
    TAGLD2(TV[10], BASEH, "1024",SC); TAGLD2(TV[11], BASEH, "1536", SC); \
    TAGLD2(TV[12], BASEH, "2048",SC); TAGLD2(TV[13], BASEH, "2560", SC); \
    TAGLD2(TV[14], BASEH, "3072",SC); TAGLD2(TV[15], BASEH, "3584", SC); \
    } while (0)

#define TAGCHECK(TV, DST) do { \
    DST = 0; \
    _Pragma("unroll") \
    for (int i2_ = 0; i2_ < 16; i2_++) \
        DST |= (TV[i2_].x ^ tagS) | (TV[i2_].y ^ tagS) | (TV[i2_].z ^ tagS) | (TV[i2_].w ^ tagS); \
    } while (0)

// validate quarter; rare stale path: serial re-poll with distress fallback.
#define VALQ(TV, BASE, BASEH) do { \
    unsigned d_; TAGCHECK(TV, d_); \
    unsigned ok_ = ((d_ & 0xFFFFu) == 0u) ? 1u : 0u; \
    if (!__all((int)ok_)) { \
        stale_ = 1u; \
        int rounds_ = 0; \
        for (;;) { \
            if (!ok_) { \
                if (!gmode) { POLLQ(TV, BASE, BASEH, "sc0"); } \
                else        { POLLQ(TV, BASE, BASEH, "sc0 sc1"); } \
                asm volatile("s_waitcnt vmcnt(0)" ::: "memory"); \
                __builtin_amdgcn_sched_barrier(0); \
                TAGCHECK(TV, d_); \
                ok_ = ((d_ & 0xFFFFu) == 0u) ? 1u : 0u; \
            } \
            ++rounds_; \
            if (__all((int)ok_)) break; \
            if ((rounds_ & 15) == 0) { \
                unsigned fl; \
                asm volatile("global_load_dword %0, %1, off sc0 sc1\n\t" \
                             "s_waitcnt vmcnt(0)" : "=v"(fl) : "v"(dflag) : "memory"); \
                bool anyfl = __any((int)(fl != 0u)); \
                if (!gmode && (anyfl || rounds_ > 96)) { \
                    if (!anyfl && lane == 0) { \
                        unsigned one_ = 1u; \
                        asm volatile("global_store_dword %0, %1, off sc0 sc1" \
                                     :: "v"(dflag), "v"(one_) : "memory"); \
                    } \
                    gmode = 1u; \
                    asm volatile("global_store_dwordx4 %0, %1, off sc0 sc1" \
                                 :: "v"(lastsp), "v"(lastow) : "memory"); \
                } \
            } \
            __builtin_amdgcn_s_sleep(1); \
        } \
    } } while (0)

#define MFMA8(TV, J0) do { \
    _Pragma("unroll") \
    for (int j3_ = 0; j3_ < 8; ++j3_) { \
        const int jj_ = (J0) + j3_; \
        u32x4 a2_ = TV[2 * j3_], b2_ = TV[2 * j3_ + 1]; \
        u32x4 f_; \
        f_.x = (a2_.x >> 16) | (a2_.y & 0xFFFF0000u); \
        f_.y = (a2_.z >> 16) | (a2_.w & 0xFFFF0000u); \
        f_.z = (b2_.x >> 16) | (b2_.y & 0xFFFF0000u); \
        f_.w = (b2_.z >> 16) | (b2_.w & 0xFFFF0000u); \
        s16x8 hfrag = __builtin_bit_cast(s16x8, f_); \
        s16x8 g = *(const s16x8*)(((jj_ & 1) ? pO : pE) + jj_ * 64); \
        ac[jj_ & 3] = __builtin_amdgcn_mfma_f32_16x16x32_bf16(g, hfrag, ac[jj_ & 3], 0, 0, 0); \
    } } while (0)

#define WAITN(NSTR) do { \
    asm volatile("s_waitcnt vmcnt(" NSTR ")" ::: "memory"); \
    __builtin_amdgcn_sched_barrier(0); } while (0)

#define STEP(S, PVUSE, PVFILL) do { \
    const char* hc32 = (const char*)hbuf32 + (((S) & 1) << 18); \
    char*       hn32 = (char*)hbuf32 + ((((S) + 1) & 1) << 18); \
    const unsigned tagS = (unsigned)(S); \
    const char* b0 = hc32 + qoff;       const char* b0h = b0 + 4096; \
    const char* b1 = b0 + 8192;         const char* b1h = b1 + 4096; \
    const char* b2 = b0 + 16384;        const char* b2h = b2 + 4096; \
    const char* b3 = b0 + 24576;        const char* b3h = b3 + 4096; \
    unsigned stale_ = 0u; \
    for (int i_ = 0; i_ < slp; ++i_) __builtin_amdgcn_s_sleep(2); \
    u32x4 tv0[16], tv1[16]; \
    f32x4 ac[4] = {}; \
    if (!gmode) { POLLQ(tv0, b0, b0h, "sc0"); POLLQ(tv1, b1, b1h, "sc0"); } \
    else        { POLLQ(tv0, b0, b0h, "sc0 sc1"); POLLQ(tv1, b1, b1h, "sc0 sc1"); } \
    WAITN("16"); \
    VALQ(tv0, b0, b0h); \
    MFMA8(tv0, 0); \
    if (!gmode) { POLLQ(tv0, b2, b2h, "sc0"); } else { POLLQ(tv0, b2, b2h, "sc0 sc1"); } \
    WAITN("16"); \
    VALQ(tv1, b1, b1h); \
    MFMA8(tv1, 8); \
    if (!gmode) { POLLQ(tv1, b3, b3h, "sc0"); } else { POLLQ(tv1, b3, b3h, "sc0 sc1"); } \
    { const int sn = ((S) + 1 < T_) ? (S) + 1 : (S); \
      PVFILL = pre_ld(pre + ((size_t)sn * B_ + hrow) * H_ + col0); } \
    WAITN("17"); \
    VALQ(tv0, b2, b2h); \
    MFMA8(tv0, 16); \
    WAITN("0"); \
    VALQ(tv1, b3, b3h); \
    MFMA8(tv1, 24); \
    f32x4 sm = (ac[0] + ac[1]) + (ac[2] + ac[3]); \
    if (l15 < 8) { \
        u32x4 ow; \
        _Pragma("unroll") \
        for (int r = 0; r < 4; r++) { \
            float v = sm[r] + to_f32(PVUSE[r]); \
            v = v >= 0.f ? v : 0.01f * v; \
            ow[r] = ((unsigned)f2bf(v) << 16) | (tagS + 1u); \
        } \
        char* sp = hn32 + sp_off; \
        if (!gmode) { \
            asm volatile("global_store_dwordx4 %0, %1, off sc0" \
                         :: "v"(sp), "v"(ow) : "memory"); \
        } else { \
            asm volatile("global_store_dwordx4 %0, %1, off sc0 sc1" \
                         :: "v"(sp), "v"(ow) : "memory"); \
        } \
        lastow = ow; lastsp = sp; \
    } \
    slp = stale_ ? (slp + 2 > 8 ? 8 : slp + 2) : (slp > 0 ? slp - 1 : 0); \
  } while (0)

template<typename PreT>
__global__ __launch_bounds__(256, 1)
void rnn_scan17(const unsigned short* __restrict__ WbotT,
                const PreT* __restrict__ pre,      // [T][B][H] t-major
                unsigned* __restrict__ hbuf32,     // [2][exchange layout] tagged u32
                unsigned* __restrict__ dflag)      // distress flag + scratch
{
    using p4_t = typename pre4<PreT>::t;
    __shared__ unsigned short Ws[64 * 1024];      // 128KiB, XOR-swizzled rows
    const int tid = threadIdx.x, lane = tid & 63, w = tid >> 6;
    const int rg = (int)blockIdx.x & 7;           // &7 -> same rg = same XCD (round-robin)
    const int cs = (int)blockIdx.x >> 3;
    const int n0 = cs * 64;

    // fill Ws swizzled: byte(r,kb) = r*2048 + (kb ^ ((r&7)<<4))
    for (int idx = tid; idx < 64 * 128; idx += 256) {
        int r = idx >> 7, kb = (idx & 127) * 16;
        s16x8 v = *(const s16x8*)(WbotT + (size_t)(n0 + r) * H_ + (idx & 127) * 8);
        *(s16x8*)((char*)Ws + r * 2048 + (kb ^ ((r & 7) << 4))) = v;
    }
    __syncthreads();

    const int l15 = lane & 15, l4 = lane >> 4;
    const int hrow = rg * 8 + (l15 & 7);          // 8 rows; lanes l15>=8 duplicate
    const int col0 = n0 + w * 16 + l4 * 4;        // 4 consecutive output cols

    // consumer poll base (q0); quarters at +8192
    const int qoff = rg * 32768 + l4 * 128 + (lane & 7) * 16;
    // producer store offset for (row=l15&7, col0..col0+3)
    const int q_ = col0 >> 8, j_ = (col0 >> 5) & 7, a_ = (col0 >> 3) & 3, p_ = (col0 >> 2) & 1;
    const int sp_off = rg * 32768 + q_ * 8192 + j_ * 1024 + p_ * 512 + (a_ * 8 + (l15 & 7)) * 16;

    // full-K Ws read bases: lane row = w*16 + l15
    const int b6 = (l15 >> 2) & 1;
    const char* wsRowF = (const char*)Ws + (size_t)(w * 16 + l15) * 2048
                       + ((l4 * 16) ^ ((l15 & 3) << 4));
    const char* pE = wsRowF + b6 * 64;   // even k-chunk jj
    const char* pO = wsRowF - b6 * 64;   // odd  k-chunk jj

    int slp = 0;                        // adaptive pre-poll sleep (per wave)
    unsigned gmode = 0;                 // 0 = XCD-local sc0, 1 = L3 sc1 (sticky)
    u32x4 lastow = {};
    char* lastsp = (char*)dflag + 1024 + tid * 16;   // harmless scratch until first store

    p4_t pvA, pvB;
    pvA = pre_ld(pre + (size_t)hrow * H_ + col0);   // pre[t=0]
    asm volatile("s_waitcnt vmcnt(0)" ::: "memory");

    for (int t = 0; t < T_; t += 2) {
        STEP(t,     pvA, pvB);
        STEP(t + 1, pvB, pvA);
    }
}

// ---------- launch ----------
extern "C" void kernel_launch(void* const* d_in, const int* in_sizes, int n_in,
                              void* d_out, int out_size, void* d_ws, size_t ws_size,
                              hipStream_t stream)
{
    const float* x     = (const float*)d_in[0];
    const float* W_in  = (const float*)d_in[1];
    const float* b_in  = (const float*)d_in[2];
    const float* W_h   = (const float*)d_in[3];
    const float* b_h   = (const float*)d_in[4];
    const float* W_out = (const float*)d_in[5];
    const float* b_out = (const float*)d_in[6];
    float* out = (float*)d_out;

    char* ws = (char*)d_ws;
    size_t off = 0;
    auto alloc = [&](size_t bytes) { void* p = ws + off; off += (bytes + 255) & ~(size_t)255; return p; };

    unsigned short* Xb    = (unsigned short*)alloc((size_t)MT_ * I_ * 2);
    unsigned short* WinT  = (unsigned short*)alloc((size_t)H_ * I_ * 2);
    unsigned short* WtopT = (unsigned short*)alloc((size_t)H_ * H_ * 2);
    unsigned short* WbotT = (unsigned short*)alloc((size_t)H_ * H_ * 2);
    unsigned short* WoutT = (unsigned short*)alloc((size_t)O_ * H_ * 2);
    unsigned short* Abuf  = (unsigned short*)alloc((size_t)MT_ * H_ * 2);
    unsigned*       hbuf32 = (unsigned*)alloc((size_t)2 * B_ * H_ * 4);   // tagged ping-pong
    unsigned*       dbuf  = (unsigned*)alloc(8192);                       // distress + scratch
    unsigned short* hfin  = (unsigned short*)alloc((size_t)B_ * H_ * 2);  // unscrambled h_T
    void* pre = ws + off;
    const bool pre_f32 = (off + (size_t)MT_ * H_ * 4) <= ws_size;

    hipMemsetAsync(hbuf32, 0, (size_t)2 * B_ * H_ * 4, stream);
    hipMemsetAsync(dbuf, 0, 8192, stream);

    cvt_x<<<2048, 256, 0, stream>>>(x, Xb, MT_ * I_);
    dim3 tb(32, 8);
    cvt_t<<<dim3(H_ / 32, I_ / 32), tb, 0, stream>>>(W_in,  WinT,  I_, H_, 0);
    cvt_t<<<dim3(H_ / 32, H_ / 32), tb, 0, stream>>>(W_h,   WtopT, H_, H_, 0);
    cvt_t<<<dim3(H_ / 32, H_ / 32), tb, 0, stream>>>(W_h,   WbotT, H_, H_, H_);
    cvt_t<<<dim3(O_ / 32, H_ / 32), tb, 0, stream>>>(W_out, WoutT, H_, O_, 0);

    // GEMM1: A = lrelu(X @ W_in + b_in)   [MT, H] bf16
    gemm_bf16<unsigned short, true, false>
        <<<dim3(MT_ / 128, H_ / 128), 256, 0, stream>>>(Xb, WinT, b_in, Abuf, MT_, I_, H_);

    // GEMM2: pre = A @ Wtop + b_h   written t-major [T][B][H] with nt stores
    if (pre_f32) {
        gemm_bf16<float, false, true>
            <<<dim3(MT_ / 128, H_ / 128), 256, 0, stream>>>(Abuf, WtopT, b_h, (float*)pre, MT_, H_, H_);
        rnn_scan17<float><<<RG_ * CS_, 256, 0, stream>>>(WbotT, (const float*)pre, hbuf32, dbuf);
    } else {
        gemm_bf16<unsigned short, false, true>
            <<<dim3(MT_ / 128, H_ / 128), 256, 0, stream>>>(Abuf, WtopT, b_h, (unsigned short*)pre, MT_, H_, H_);
        rnn_scan17<unsigned short><<<RG_ * CS_, 256, 0, stream>>>(WbotT, (const unsigned short*)pre, hbuf32, dbuf);
    }

    // h_T in slot 0 (tag 1024); unscramble (end-of-dispatch flush makes it coherent)
    strip_h<<<64, 256, 0, stream>>>(hbuf32, hfin);
    gemm_bf16<float, false, false>
        <<<dim3(1, O_ / 128), 256, 0, stream>>>(hfin, WoutT, b_out, out, B_, H_, O_);
}

// Round 18
// 3317.707 us; speedup vs baseline: 1.5042x; 1.5042x over previous
//
#include <hip/hip_runtime.h>
#include <hip/hip_bf16.h>

// ---------- types ----------
typedef __attribute__((ext_vector_type(8))) short  s16x8;
typedef __attribute__((ext_vector_type(4))) float  f32x4;
typedef __attribute__((ext_vector_type(4))) unsigned short u16x4;
typedef __attribute__((ext_vector_type(4))) unsigned int   u32x4;

#define B_  64
#define T_  1024
#define I_  512
#define H_  1024
#define O_  512
#define MT_ 65536   // B_*T_

// scan decomposition: 8 row-groups (8 rows, rg = blockIdx&7 -> one XCD under
// round-robin dispatch) x 16 col-slices; 4 waves split K. 128 blocks.
#define RG_   8
#define CS_   16

// ---------- helpers ----------
__device__ __forceinline__ unsigned short f2bf(float f) {
    unsigned u = __builtin_bit_cast(unsigned, f);
    u += 0x7FFFu + ((u >> 16) & 1u);
    return (unsigned short)(u >> 16);
}
__device__ __forceinline__ float bf2f(unsigned short h) {
    return __builtin_bit_cast(float, ((unsigned)h) << 16);
}
__device__ __forceinline__ void store_out(float* p, float v) { *p = v; }
__device__ __forceinline__ void store_out(unsigned short* p, float v) { *p = f2bf(v); }
__device__ __forceinline__ void store_nt(float* p, float v) {
    asm volatile("global_store_dword %0, %1, off nt" :: "v"(p), "v"(v) : "memory");
}
__device__ __forceinline__ void store_nt(unsigned short* p, float v) {
    unsigned short h = f2bf(v);
    asm volatile("global_store_short %0, %1, off nt" :: "v"(p), "v"(h) : "memory");
}
__device__ __forceinline__ float to_f32(float v) { return v; }
__device__ __forceinline__ float to_f32(unsigned short v) { return bf2f(v); }

template<typename T> struct pre4;
template<> struct pre4<float>          { using t = f32x4; };
template<> struct pre4<unsigned short> { using t = u16x4; };

__device__ __forceinline__ f32x4 pre_ld(const float* p) {
    f32x4 d; asm volatile("global_load_dwordx4 %0, %1, off nt" : "=v"(d) : "v"(p)); return d;
}
__device__ __forceinline__ u16x4 pre_ld(const unsigned short* p) {
    u16x4 d; asm volatile("global_load_dwordx2 %0, %1, off nt" : "=v"(d) : "v"(p)); return d;
}

#define GL2LDS16(gp, lp) __builtin_amdgcn_global_load_lds( \
    (const __attribute__((address_space(1))) void*)(gp),   \
    (__attribute__((address_space(3))) void*)(lp), 16, 0, 0)

// ---------- conversion kernels ----------
__global__ void cvt_x(const float* __restrict__ src, unsigned short* __restrict__ dst, int n) {
    int stride = gridDim.x * blockDim.x * 4;
    for (int i = (blockIdx.x * blockDim.x + threadIdx.x) * 4; i < n; i += stride) {
        const float4 v = *(const float4*)(src + i);
        u16x4 o;
        o.x = f2bf(v.x); o.y = f2bf(v.y); o.z = f2bf(v.z); o.w = f2bf(v.w);
        *(u16x4*)(dst + i) = o;
    }
}

// dst[c][r] = bf16(src[row_off + r][c]);  src region [SR,SC] row-major -> dst [SC,SR]
__global__ void cvt_t(const float* __restrict__ src, unsigned short* __restrict__ dst,
                      int SR, int SC, int row_off) {
    __shared__ unsigned short tile[32][33];
    int c0 = blockIdx.x * 32, r0 = blockIdx.y * 32;
    int tx = threadIdx.x, ty = threadIdx.y;
    #pragma unroll
    for (int i = 0; i < 32; i += 8)
        tile[ty + i][tx] = f2bf(src[(size_t)(row_off + r0 + ty + i) * SC + c0 + tx]);
    __syncthreads();
    #pragma unroll
    for (int i = 0; i < 32; i += 8)
        dst[(size_t)(c0 + ty + i) * SR + r0 + tx] = tile[tx][ty + i];
}

// unscramble exchange layout (slot 0) -> row-major bf16 h_T.
__global__ void strip_h(const unsigned* __restrict__ src, unsigned short* __restrict__ dst) {
    int idx = blockIdx.x * blockDim.x + threadIdx.x;   // 16384 chunks
    u32x4 v = *(const u32x4*)(src + idx * 4);
    int rg = idx >> 11, c2 = idx & 2047;
    int q = c2 >> 9, c3 = c2 & 511;
    int j = c3 >> 6, c = c3 & 63;
    int p = c >> 5, a = (c >> 3) & 3, row = c & 7;
    int grow = rg * 8 + row;
    int col = q * 256 + j * 32 + a * 8 + p * 4;
    u16x4 o;
    o.x = (unsigned short)(v.x >> 16); o.y = (unsigned short)(v.y >> 16);
    o.z = (unsigned short)(v.z >> 16); o.w = (unsigned short)(v.w >> 16);
    *(u16x4*)(dst + (size_t)grow * H_ + col) = o;
}

// ---------- generic bf16 MFMA GEMM: C[M,N] = act(A[M,K] @ BT[N,K]^T + bias) ----------
template<typename OutT, bool LRELU, bool SCATTER>
__global__ __launch_bounds__(256)
void gemm_bf16(const unsigned short* __restrict__ A,
               const unsigned short* __restrict__ BT,
               const float* __restrict__ bias,
               OutT* __restrict__ C, int M, int K, int N)
{
    __shared__ unsigned short As[4096]; // [128][32]
    __shared__ unsigned short Bs[4096]; // [128][32]
    const int tid = threadIdx.x, lane = tid & 63, wid = tid >> 6;
    const int wr = wid >> 1, wc = wid & 1;
    const int m0 = blockIdx.x * 128, n0 = blockIdx.y * 128;

    f32x4 acc[4][4] = {};

    const int c = wid * 2;
    const int srow = lane >> 2;
    const int scol = (lane & 3) * 8;
    const unsigned short* Ag0 = A  + (size_t)(m0 + c * 16 + srow) * K + scol;
    const unsigned short* Ag1 = A  + (size_t)(m0 + c * 16 + 16 + srow) * K + scol;
    const unsigned short* Bg0 = BT + (size_t)(n0 + c * 16 + srow) * K + scol;
    const unsigned short* Bg1 = BT + (size_t)(n0 + c * 16 + 16 + srow) * K + scol;

    for (int k0 = 0; k0 < K; k0 += 32) {
        __syncthreads();
        GL2LDS16(Ag0 + k0, As + c * 512);
        GL2LDS16(Ag1 + k0, As + (c + 1) * 512);
        GL2LDS16(Bg0 + k0, Bs + c * 512);
        GL2LDS16(Bg1 + k0, Bs + (c + 1) * 512);
        __syncthreads();

        s16x8 af[4], bfr[4];
        #pragma unroll
        for (int i = 0; i < 4; i++)
            af[i] = *(const s16x8*)(As + (wr * 64 + i * 16 + (lane & 15)) * 32 + (lane >> 4) * 8);
        #pragma unroll
        for (int j = 0; j < 4; j++)
            bfr[j] = *(const s16x8*)(Bs + (wc * 64 + j * 16 + (lane & 15)) * 32 + (lane >> 4) * 8);
        #pragma unroll
        for (int i = 0; i < 4; i++)
            #pragma unroll
            for (int j = 0; j < 4; j++)
                acc[i][j] = __builtin_amdgcn_mfma_f32_16x16x32_bf16(af[i], bfr[j], acc[i][j], 0, 0, 0);
    }

    #pragma unroll
    for (int j = 0; j < 4; j++) {
        const int n = n0 + wc * 64 + j * 16 + (lane & 15);
        const float bv = bias[n];
        #pragma unroll
        for (int i = 0; i < 4; i++) {
            #pragma unroll
            for (int r = 0; r < 4; r++) {
                const int m = m0 + wr * 64 + i * 16 + (lane >> 4) * 4 + r;
                if (m < M) {
                    float v = acc[i][j][r] + bv;
                    if (LRELU) v = v >= 0.f ? v : 0.01f * v;
                    if (SCATTER) {
                        size_t row = (size_t)((m & (T_ - 1)) * B_ + (m >> 10));
                        store_nt(&C[row * N + n], v);
                    } else {
                        store_out(&C[(size_t)m * N + n], v);
                    }
                }
            }
        }
    }
}

// ---------- scan v18: r15 (XCD-local sc0 exchange, K-split waves) minus jitter ----
// Deltas vs r15 (the 2397us best): (1) NO pre-poll sleep in the fast path — the
// adaptive controller added 0.2-0.4us deliberate sleep per step and persistent
// per-wave skew that lands on the rg-wide max; polls are L2-cheap now. (2) pbuf
// double-buffered by step parity -> the trailing WAR barrier is unnecessary
// (next step writes the other buffer); ONE barrier per step. Protocol, layout,
// and distress fallback unchanged.

#define TAGLD2(d, BASE, OFFSTR, SC) asm volatile( \
    "global_load_dwordx4 %0, %1, off offset:" OFFSTR " " SC \
    : "=v"(d) : "v"(BASE))

#define POLLBODY(SC) do { \
    TAGLD2(tv[0],  tA, "0",   SC); TAGLD2(tv[1],  tA, "512",  SC); \
    TAGLD2(tv[2],  tA, "1024",SC); TAGLD2(tv[3],  tA, "1536", SC); \
    TAGLD2(tv[4],  tA, "2048",SC); TAGLD2(tv[5],  tA, "2560", SC); \
    TAGLD2(tv[6],  tA, "3072",SC); TAGLD2(tv[7],  tA, "3584", SC); \
    TAGLD2(tv[8],  tB, "0",   SC); TAGLD2(tv[9],  tB, "512",  SC); \
    TAGLD2(tv[10], tB, "1024",SC); TAGLD2(tv[11], tB, "1536", SC); \
    TAGLD2(tv[12], tB, "2048",SC); TAGLD2(tv[13], tB, "2560", SC); \
    TAGLD2(tv[14], tB, "3072",SC); TAGLD2(tv[15], tB, "3584", SC); \
    } while (0)

#define STEP(S, PVUSE, PVFILL) do { \
    const char* hc32 = (const char*)hbuf32 + (((S) & 1) << 18); \
    char*       hn32 = (char*)hbuf32 + ((((S) + 1) & 1) << 18); \
    const unsigned tagS = (unsigned)(S); \
    const char* tA = hc32 + tbA_off; \
    const char* tB = tA + 4096; \
    float* pb = pbuf + ((S) & 1) * 2176; \
    u32x4 tv[16]; \
    unsigned ok = 0u; \
    int rounds_ = 0; \
    for (;;) { \
        if (!ok) { \
            if (!gmode) { POLLBODY("sc0"); } else { POLLBODY("sc0 sc1"); } \
            asm volatile("s_waitcnt vmcnt(0)" ::: "memory"); \
            __builtin_amdgcn_sched_barrier(0); \
            unsigned d_ = 0; \
            _Pragma("unroll") \
            for (int i = 0; i < 16; i++) \
                d_ |= (tv[i].x ^ tagS) | (tv[i].y ^ tagS) | (tv[i].z ^ tagS) | (tv[i].w ^ tagS); \
            ok = ((d_ & 0xFFFFu) == 0u) ? 1u : 0u; \
        } \
        ++rounds_; \
        if (__all((int)ok)) break; \
        if ((rounds_ & 15) == 0) { \
            unsigned fl; \
            asm volatile("global_load_dword %0, %1, off sc0 sc1\n\t" \
                         "s_waitcnt vmcnt(0)" : "=v"(fl) : "v"(dflag) : "memory"); \
            bool anyfl = __any((int)(fl != 0u)); \
            if (!gmode && (anyfl || rounds_ > 96)) { \
                if (!anyfl && lane == 0) { \
                    unsigned one_ = 1u; \
                    asm volatile("global_store_dword %0, %1, off sc0 sc1" \
                                 :: "v"(dflag), "v"(one_) : "memory"); \
                } \
                gmode = 1u; \
                asm volatile("global_store_dwordx4 %0, %1, off sc0 sc1" \
                             :: "v"(lastsp), "v"(lastow) : "memory"); \
            } \
            __builtin_amdgcn_s_sleep(1); \
        } \
    } \
    { const int sn = ((S) + 1 < T_) ? (S) + 1 : (S); \
      PVFILL = pre_ld(pre + ((size_t)sn * B_ + hrow) * H_ + col0); } \
    f32x4 ac[4] = {}; \
    _Pragma("unroll") \
    for (int cg = 0; cg < 4; ++cg) { \
        const char* pE = wE + cg * 32768; \
        const char* pO = wO + cg * 32768; \
        _Pragma("unroll") \
        for (int j = 0; j < 8; ++j) { \
            u32x4 a2_ = tv[2 * j], b2_ = tv[2 * j + 1]; \
            u32x4 f_; \
            f_.x = (a2_.x >> 16) | (a2_.y & 0xFFFF0000u); \
            f_.y = (a2_.z >> 16) | (a2_.w & 0xFFFF0000u); \
            f_.z = (b2_.x >> 16) | (b2_.y & 0xFFFF0000u); \
            f_.w = (b2_.z >> 16) | (b2_.w & 0xFFFF0000u); \
            s16x8 hfrag = __builtin_bit_cast(s16x8, f_); \
            s16x8 g = *(const s16x8*)(((j & 1) ? pO : pE) + j * 64); \
            ac[cg] = __builtin_amdgcn_mfma_f32_16x16x32_bf16(g, hfrag, ac[cg], 0, 0, 0); \
        } \
    } \
    if (l15 < 8) { \
        float* pw_ = pb + (w * 8 + l15) * 68 + l4 * 4; \
        *(f32x4*)(pw_ +  0) = ac[0]; \
        *(f32x4*)(pw_ + 16) = ac[1]; \
        *(f32x4*)(pw_ + 32) = ac[2]; \
        *(f32x4*)(pw_ + 48) = ac[3]; \
    } \
    asm volatile("s_waitcnt lgkmcnt(0)" ::: "memory"); \
    __builtin_amdgcn_s_barrier(); \
    asm volatile("" ::: "memory"); \
    if (l15 < 8) { \
        const float* pr_ = pb + l15 * 68 + w * 16 + l4 * 4; \
        f32x4 s0 = *(const f32x4*)(pr_); \
        f32x4 s1 = *(const f32x4*)(pr_ + 544); \
        f32x4 s2 = *(const f32x4*)(pr_ + 1088); \
        f32x4 s3 = *(const f32x4*)(pr_ + 1632); \
        f32x4 sm = (s0 + s1) + (s2 + s3); \
        u32x4 ow; \
        _Pragma("unroll") \
        for (int r = 0; r < 4; r++) { \
            float v = sm[r] + to_f32(PVUSE[r]); \
            v = v >= 0.f ? v : 0.01f * v; \
            ow[r] = ((unsigned)f2bf(v) << 16) | (tagS + 1u); \
        } \
        char* sp = hn32 + sp_off; \
        if (!gmode) { \
            asm volatile("global_store_dwordx4 %0, %1, off sc0" \
                         :: "v"(sp), "v"(ow) : "memory"); \
        } else { \
            asm volatile("global_store_dwordx4 %0, %1, off sc0 sc1" \
                         :: "v"(sp), "v"(ow) : "memory"); \
        } \
        lastow = ow; lastsp = sp; \
    } \
  } while (0)

template<typename PreT>
__global__ __launch_bounds__(256, 1)
void rnn_scan18(const unsigned short* __restrict__ WbotT,
                const PreT* __restrict__ pre,      // [T][B][H] t-major
                unsigned* __restrict__ hbuf32,     // [2][exchange layout] tagged u32
                unsigned* __restrict__ dflag)      // distress flag + scratch
{
    using p4_t = typename pre4<PreT>::t;
    __shared__ unsigned short Ws[64 * 1024];      // 128KiB, XOR-swizzled rows
    __shared__ float pbuf[2 * 2176];              // 17.4KB double-buffered partials
    const int tid = threadIdx.x, lane = tid & 63, w = tid >> 6;
    const int rg = (int)blockIdx.x & 7;           // &7 -> same rg = same XCD (round-robin)
    const int cs = (int)blockIdx.x >> 3;
    const int n0 = cs * 64;

    // fill Ws swizzled: byte(r,kb) = r*2048 + (kb ^ ((r&7)<<4))
    for (int idx = tid; idx < 64 * 128; idx += 256) {
        int r = idx >> 7, kb = (idx & 127) * 16;
        s16x8 v = *(const s16x8*)(WbotT + (size_t)(n0 + r) * H_ + (idx & 127) * 8);
        *(s16x8*)((char*)Ws + r * 2048 + (kb ^ ((r & 7) << 4))) = v;
    }
    __syncthreads();

    const int l15 = lane & 15, l4 = lane >> 4;
    const int hrow = rg * 8 + (l15 & 7);          // 8 rows; lanes l15>=8 duplicate
    const int col0 = n0 + w * 16 + l4 * 4;        // 4 consecutive output cols

    // consumer poll base (wave w = k-quarter q): lane -> (a=lane>>4, row=lane&7)
    const int tbA_off = rg * 32768 + w * 8192 + (lane >> 4) * 128 + (lane & 7) * 16;
    // producer store offset for (row=l15&7, col0..col0+3)
    const int q_ = col0 >> 8, j_ = (col0 >> 5) & 7, a_ = (col0 >> 3) & 3, p_ = (col0 >> 2) & 1;
    const int sp_off = rg * 32768 + q_ * 8192 + j_ * 1024 + p_ * 512 + (a_ * 8 + (l15 & 7)) * 16;

    // swizzled Ws read bases (unchanged from r15)
    const int b6 = (l15 >> 2) & 1;
    const char* wsRow = (const char*)Ws + l15 * 2048 + ((l4 * 16) ^ ((l15 & 3) << 4)) + w * 512;
    const char* wE = wsRow + b6 * 64;   // even j
    const char* wO = wsRow - b6 * 64;   // odd j

    unsigned gmode = 0;                 // 0 = XCD-local sc0, 1 = L3 sc1 (sticky)
    u32x4 lastow = {};
    char* lastsp = (char*)dflag + 1024 + tid * 16;   // harmless scratch until first store

    p4_t pvA, pvB;
    pvA = pre_ld(pre + (size_t)hrow * H_ + col0);   // pre[t=0]
    asm volatile("s_waitcnt vmcnt(0)" ::: "memory");

    for (int t = 0; t < T_; t += 2) {
        STEP(t,     pvA, pvB);
        STEP(t + 1, pvB, pvA);
    }
}

// ---------- launch ----------
extern "C" void kernel_launch(void* const* d_in, const int* in_sizes, int n_in,
                              void* d_out, int out_size, void* d_ws, size_t ws_size,
                              hipStream_t stream)
{
    const float* x     = (const float*)d_in[0];
    const float* W_in  = (const float*)d_in[1];
    const float* b_in  = (const float*)d_in[2];
    const float* W_h   = (const float*)d_in[3];
    const float* b_h   = (const float*)d_in[4];
    const float* W_out = (const float*)d_in[5];
    const float* b_out = (const float*)d_in[6];
    float* out = (float*)d_out;

    char* ws = (char*)d_ws;
    size_t off = 0;
    auto alloc = [&](size_t bytes) { void* p = ws + off; off += (bytes + 255) & ~(size_t)255; return p; };

    unsigned short* Xb    = (unsigned short*)alloc((size_t)MT_ * I_ * 2);
    unsigned short* WinT  = (unsigned short*)alloc((size_t)H_ * I_ * 2);
    unsigned short* WtopT = (unsigned short*)alloc((size_t)H_ * H_ * 2);
    unsigned short* WbotT = (unsigned short*)alloc((size_t)H_ * H_ * 2);
    unsigned short* WoutT = (unsigned short*)alloc((size_t)O_ * H_ * 2);
    unsigned short* Abuf  = (unsigned short*)alloc((size_t)MT_ * H_ * 2);
    unsigned*       hbuf32 = (unsigned*)alloc((size_t)2 * B_ * H_ * 4);   // tagged ping-pong
    unsigned*       dbuf  = (unsigned*)alloc(8192);                       // distress + scratch
    unsigned short* hfin  = (unsigned short*)alloc((size_t)B_ * H_ * 2);  // unscrambled h_T
    void* pre = ws + off;
    const bool pre_f32 = (off + (size_t)MT_ * H_ * 4) <= ws_size;

    hipMemsetAsync(hbuf32, 0, (size_t)2 * B_ * H_ * 4, stream);
    hipMemsetAsync(dbuf, 0, 8192, stream);

    cvt_x<<<2048, 256, 0, stream>>>(x, Xb, MT_ * I_);
    dim3 tb(32, 8);
    cvt_t<<<dim3(H_ / 32, I_ / 32), tb, 0, stream>>>(W_in,  WinT,  I_, H_, 0);
    cvt_t<<<dim3(H_ / 32, H_ / 32), tb, 0, stream>>>(W_h,   WtopT, H_, H_, 0);
    cvt_t<<<dim3(H_ / 32, H_ / 32), tb, 0, stream>>>(W_h,   WbotT, H_, H_, H_);
    cvt_t<<<dim3(O_ / 32, H_ / 32), tb, 0, stream>>>(W_out, WoutT, H_, O_, 0);

    // GEMM1: A = lrelu(X @ W_in + b_in)   [MT, H] bf16
    gemm_bf16<unsigned short, true, false>
        <<<dim3(MT_ / 128, H_ / 128), 256, 0, stream>>>(Xb, WinT, b_in, Abuf, MT_, I_, H_);

    // GEMM2: pre = A @ Wtop + b_h   written t-major [T][B][H] with nt stores
    if (pre_f32) {
        gemm_bf16<float, false, true>
            <<<dim3(MT_ / 128, H_ / 128), 256, 0, stream>>>(Abuf, WtopT, b_h, (float*)pre, MT_, H_, H_);
        rnn_scan18<float><<<RG_ * CS_, 256, 0, stream>>>(WbotT, (const float*)pre, hbuf32, dbuf);
    } else {
        gemm_bf16<unsigned short, false, true>
            <<<dim3(MT_ / 128, H_ / 128), 256, 0, stream>>>(Abuf, WtopT, b_h, (unsigned short*)pre, MT_, H_, H_);
        rnn_scan18<unsigned short><<<RG_ * CS_, 256, 0, stream>>>(WbotT, (const unsigned short*)pre, hbuf32, dbuf);
    }

    // h_T in slot 0 (tag 1024); unscramble (end-of-dispatch flush makes it coherent)
    strip_h<<<64, 256, 0, stream>>>(hbuf32, hfin);
    gemm_bf16<float, false, false>
        <<<dim3(1, O_ / 128), 256, 0, stream>>>(hfin, WoutT, b_out, out, B_, H_, O_);
}

// Round 19
// 2874.842 us; speedup vs baseline: 1.7359x; 1.1540x over previous
//
#include <hip/hip_runtime.h>
#include <hip/hip_bf16.h>

// ---------- types ----------
typedef __attribute__((ext_vector_type(8))) short  s16x8;
typedef __attribute__((ext_vector_type(4))) float  f32x4;
typedef __attribute__((ext_vector_type(4))) unsigned short u16x4;
typedef __attribute__((ext_vector_type(4))) unsigned int   u32x4;

#define B_  64
#define T_  1024
#define I_  512
#define H_  1024
#define O_  512
#define MT_ 65536   // B_*T_

// scan decomposition: 8 row-groups (8 rows, rg = blockIdx&7 -> one XCD under
// round-robin dispatch) x 16 col-slices; 4 waves split K. 128 blocks.
#define RG_   8
#define CS_   16

// ---------- helpers ----------
__device__ __forceinline__ unsigned short f2bf(float f) {
    unsigned u = __builtin_bit_cast(unsigned, f);
    u += 0x7FFFu + ((u >> 16) & 1u);
    return (unsigned short)(u >> 16);
}
__device__ __forceinline__ float bf2f(unsigned short h) {
    return __builtin_bit_cast(float, ((unsigned)h) << 16);
}
__device__ __forceinline__ void store_out(float* p, float v) { *p = v; }
__device__ __forceinline__ void store_out(unsigned short* p, float v) { *p = f2bf(v); }
__device__ __forceinline__ void store_nt(float* p, float v) {
    asm volatile("global_store_dword %0, %1, off nt" :: "v"(p), "v"(v) : "memory");
}
__device__ __forceinline__ void store_nt(unsigned short* p, float v) {
    unsigned short h = f2bf(v);
    asm volatile("global_store_short %0, %1, off nt" :: "v"(p), "v"(h) : "memory");
}
__device__ __forceinline__ float to_f32(float v) { return v; }
__device__ __forceinline__ float to_f32(unsigned short v) { return bf2f(v); }

template<typename T> struct pre4;
template<> struct pre4<float>          { using t = f32x4; };
template<> struct pre4<unsigned short> { using t = u16x4; };

__device__ __forceinline__ f32x4 pre_ld(const float* p) {
    f32x4 d; asm volatile("global_load_dwordx4 %0, %1, off nt" : "=v"(d) : "v"(p)); return d;
}
__device__ __forceinline__ u16x4 pre_ld(const unsigned short* p) {
    u16x4 d; asm volatile("global_load_dwordx2 %0, %1, off nt" : "=v"(d) : "v"(p)); return d;
}

#define GL2LDS16(gp, lp) __builtin_amdgcn_global_load_lds( \
    (const __attribute__((address_space(1))) void*)(gp),   \
    (__attribute__((address_space(3))) void*)(lp), 16, 0, 0)

// ---------- conversion kernels ----------
__global__ void cvt_x(const float* __restrict__ src, unsigned short* __restrict__ dst, int n) {
    int stride = gridDim.x * blockDim.x * 4;
    for (int i = (blockIdx.x * blockDim.x + threadIdx.x) * 4; i < n; i += stride) {
        const float4 v = *(const float4*)(src + i);
        u16x4 o;
        o.x = f2bf(v.x); o.y = f2bf(v.y); o.z = f2bf(v.z); o.w = f2bf(v.w);
        *(u16x4*)(dst + i) = o;
    }
}

// dst[c][r] = bf16(src[row_off + r][c]);  src region [SR,SC] row-major -> dst [SC,SR]
__global__ void cvt_t(const float* __restrict__ src, unsigned short* __restrict__ dst,
                      int SR, int SC, int row_off) {
    __shared__ unsigned short tile[32][33];
    int c0 = blockIdx.x * 32, r0 = blockIdx.y * 32;
    int tx = threadIdx.x, ty = threadIdx.y;
    #pragma unroll
    for (int i = 0; i < 32; i += 8)
        tile[ty + i][tx] = f2bf(src[(size_t)(row_off + r0 + ty + i) * SC + c0 + tx]);
    __syncthreads();
    #pragma unroll
    for (int i = 0; i < 32; i += 8)
        dst[(size_t)(c0 + ty + i) * SR + r0 + tx] = tile[tx][ty + i];
}

// unscramble exchange layout (slot 0) -> row-major bf16 h_T.
__global__ void strip_h(const unsigned* __restrict__ src, unsigned short* __restrict__ dst) {
    int idx = blockIdx.x * blockDim.x + threadIdx.x;   // 16384 chunks
    u32x4 v = *(const u32x4*)(src + idx * 4);
    int rg = idx >> 11, c2 = idx & 2047;
    int q = c2 >> 9, c3 = c2 & 511;
    int j = c3 >> 6, c = c3 & 63;
    int p = c >> 5, a = (c >> 3) & 3, row = c & 7;
    int grow = rg * 8 + row;
    int col = q * 256 + j * 32 + a * 8 + p * 4;
    u16x4 o;
    o.x = (unsigned short)(v.x >> 16); o.y = (unsigned short)(v.y >> 16);
    o.z = (unsigned short)(v.z >> 16); o.w = (unsigned short)(v.w >> 16);
    *(u16x4*)(dst + (size_t)grow * H_ + col) = o;
}

// ---------- generic bf16 MFMA GEMM: C[M,N] = act(A[M,K] @ BT[N,K]^T + bias) ----------
template<typename OutT, bool LRELU, bool SCATTER>
__global__ __launch_bounds__(256)
void gemm_bf16(const unsigned short* __restrict__ A,
               const unsigned short* __restrict__ BT,
               const float* __restrict__ bias,
               OutT* __restrict__ C, int M, int K, int N)
{
    __shared__ unsigned short As[4096]; // [128][32]
    __shared__ unsigned short Bs[4096]; // [128][32]
    const int tid = threadIdx.x, lane = tid & 63, wid = tid >> 6;
    const int wr = wid >> 1, wc = wid & 1;
    const int m0 = blockIdx.x * 128, n0 = blockIdx.y * 128;

    f32x4 acc[4][4] = {};

    const int c = wid * 2;
    const int srow = lane >> 2;
    const int scol = (lane & 3) * 8;
    const unsigned short* Ag0 = A  + (size_t)(m0 + c * 16 + srow) * K + scol;
    const unsigned short* Ag1 = A  + (size_t)(m0 + c * 16 + 16 + srow) * K + scol;
    const unsigned short* Bg0 = BT + (size_t)(n0 + c * 16 + srow) * K + scol;
    const unsigned short* Bg1 = BT + (size_t)(n0 + c * 16 + 16 + srow) * K + scol;

    for (int k0 = 0; k0 < K; k0 += 32) {
        __syncthreads();
        GL2LDS16(Ag0 + k0, As + c * 512);
        GL2LDS16(Ag1 + k0, As + (c + 1) * 512);
        GL2LDS16(Bg0 + k0, Bs + c * 512);
        GL2LDS16(Bg1 + k0, Bs + (c + 1) * 512);
        __syncthreads();

        s16x8 af[4], bfr[4];
        #pragma unroll
        for (int i = 0; i < 4; i++)
            af[i] = *(const s16x8*)(As + (wr * 64 + i * 16 + (lane & 15)) * 32 + (lane >> 4) * 8);
        #pragma unroll
        for (int j = 0; j < 4; j++)
            bfr[j] = *(const s16x8*)(Bs + (wc * 64 + j * 16 + (lane & 15)) * 32 + (lane >> 4) * 8);
        #pragma unroll
        for (int i = 0; i < 4; i++)
            #pragma unroll
            for (int j = 0; j < 4; j++)
                acc[i][j] = __builtin_amdgcn_mfma_f32_16x16x32_bf16(af[i], bfr[j], acc[i][j], 0, 0, 0);
    }

    #pragma unroll
    for (int j = 0; j < 4; j++) {
        const int n = n0 + wc * 64 + j * 16 + (lane & 15);
        const float bv = bias[n];
        #pragma unroll
        for (int i = 0; i < 4; i++) {
            #pragma unroll
            for (int r = 0; r < 4; r++) {
                const int m = m0 + wr * 64 + i * 16 + (lane >> 4) * 4 + r;
                if (m < M) {
                    float v = acc[i][j][r] + bv;
                    if (LRELU) v = v >= 0.f ? v : 0.01f * v;
                    if (SCATTER) {
                        size_t row = (size_t)((m & (T_ - 1)) * B_ + (m >> 10));
                        store_nt(&C[row * N + n], v);
                    } else {
                        store_out(&C[(size_t)m * N + n], v);
                    }
                }
            }
        }
    }
}

// ---------- scan v19: r15 (best: XCD-local sc0, adaptive sleep) + single barrier ----
// r18 lesson: the adaptive pre-poll sleep is load PACING, not waste — removing it
// cost +18% (L2 poll-flood slows producers). v19 = r15 verbatim, EXCEPT pbuf is
// double-buffered by step parity so the trailing WAR barrier is provably
// unnecessary -> ONE s_barrier per step (r18's only good delta, kept).

#define TAGLD2(d, BASE, OFFSTR, SC) asm volatile( \
    "global_load_dwordx4 %0, %1, off offset:" OFFSTR " " SC \
    : "=v"(d) : "v"(BASE))

#define POLLBODY(SC) do { \
    TAGLD2(tv[0],  tA, "0",   SC); TAGLD2(tv[1],  tA, "512",  SC); \
    TAGLD2(tv[2],  tA, "1024",SC); TAGLD2(tv[3],  tA, "1536", SC); \
    TAGLD2(tv[4],  tA, "2048",SC); TAGLD2(tv[5],  tA, "2560", SC); \
    TAGLD2(tv[6],  tA, "3072",SC); TAGLD2(tv[7],  tA, "3584", SC); \
    TAGLD2(tv[8],  tB, "0",   SC); TAGLD2(tv[9],  tB, "512",  SC); \
    TAGLD2(tv[10], tB, "1024",SC); TAGLD2(tv[11], tB, "1536", SC); \
    TAGLD2(tv[12], tB, "2048",SC); TAGLD2(tv[13], tB, "2560", SC); \
    TAGLD2(tv[14], tB, "3072",SC); TAGLD2(tv[15], tB, "3584", SC); \
    } while (0)

#define STEP(S, PVUSE, PVFILL) do { \
    const char* hc32 = (const char*)hbuf32 + (((S) & 1) << 18); \
    char*       hn32 = (char*)hbuf32 + ((((S) + 1) & 1) << 18); \
    const unsigned tagS = (unsigned)(S); \
    const char* tA = hc32 + tbA_off; \
    const char* tB = tA + 4096; \
    float* pb = pbuf + ((S) & 1) * 2176; \
    for (int i_ = 0; i_ < slp; ++i_) __builtin_amdgcn_s_sleep(2); \
    u32x4 tv[16]; \
    unsigned ok = 0u; \
    int rounds_ = 0; \
    for (;;) { \
        if (!ok) { \
            if (!gmode) { POLLBODY("sc0"); } else { POLLBODY("sc0 sc1"); } \
            asm volatile("s_waitcnt vmcnt(0)" ::: "memory"); \
            __builtin_amdgcn_sched_barrier(0); \
            unsigned d_ = 0; \
            _Pragma("unroll") \
            for (int i = 0; i < 16; i++) \
                d_ |= (tv[i].x ^ tagS) | (tv[i].y ^ tagS) | (tv[i].z ^ tagS) | (tv[i].w ^ tagS); \
            ok = ((d_ & 0xFFFFu) == 0u) ? 1u : 0u; \
        } \
        ++rounds_; \
        if (__all((int)ok)) break; \
        if ((rounds_ & 15) == 0) { \
            unsigned fl; \
            asm volatile("global_load_dword %0, %1, off sc0 sc1\n\t" \
                         "s_waitcnt vmcnt(0)" : "=v"(fl) : "v"(dflag) : "memory"); \
            bool anyfl = __any((int)(fl != 0u)); \
            if (!gmode && (anyfl || rounds_ > 96)) { \
                if (!anyfl && lane == 0) { \
                    unsigned one_ = 1u; \
                    asm volatile("global_store_dword %0, %1, off sc0 sc1" \
                                 :: "v"(dflag), "v"(one_) : "memory"); \
                } \
                gmode = 1u; \
                asm volatile("global_store_dwordx4 %0, %1, off sc0 sc1" \
                             :: "v"(lastsp), "v"(lastow) : "memory"); \
            } \
        } \
        __builtin_amdgcn_s_sleep(1); \
    } \
    slp = (rounds_ > 1) ? (slp + 4 > 24 ? 24 : slp + 4) : (slp > 0 ? slp - 1 : 0); \
    { const int sn = ((S) + 1 < T_) ? (S) + 1 : (S); \
      PVFILL = pre_ld(pre + ((size_t)sn * B_ + hrow) * H_ + col0); } \
    f32x4 ac[4] = {}; \
    _Pragma("unroll") \
    for (int cg = 0; cg < 4; ++cg) { \
        const char* pE = wE + cg * 32768; \
        const char* pO = wO + cg * 32768; \
        _Pragma("unroll") \
        for (int j = 0; j < 8; ++j) { \
            u32x4 a2_ = tv[2 * j], b2_ = tv[2 * j + 1]; \
            u32x4 f_; \
            f_.x = (a2_.x >> 16) | (a2_.y & 0xFFFF0000u); \
            f_.y = (a2_.z >> 16) | (a2_.w & 0xFFFF0000u); \
            f_.z = (b2_.x >> 16) | (b2_.y & 0xFFFF0000u); \
            f_.w = (b2_.z >> 16) | (b2_.w & 0xFFFF0000u); \
            s16x8 hfrag = __builtin_bit_cast(s16x8, f_); \
            s16x8 g = *(const s16x8*)(((j & 1) ? pO : pE) + j * 64); \
            ac[cg] = __builtin_amdgcn_mfma_f32_16x16x32_bf16(g, hfrag, ac[cg], 0, 0, 0); \
        } \
    } \
    if (l15 < 8) { \
        float* pw_ = pb + (w * 8 + l15) * 68 + l4 * 4; \
        *(f32x4*)(pw_ +  0) = ac[0]; \
        *(f32x4*)(pw_ + 16) = ac[1]; \
        *(f32x4*)(pw_ + 32) = ac[2]; \
        *(f32x4*)(pw_ + 48) = ac[3]; \
    } \
    asm volatile("s_waitcnt lgkmcnt(0)" ::: "memory"); \
    __builtin_amdgcn_s_barrier(); \
    asm volatile("" ::: "memory"); \
    if (l15 < 8) { \
        const float* pr_ = pb + l15 * 68 + w * 16 + l4 * 4; \
        f32x4 s0 = *(const f32x4*)(pr_); \
        f32x4 s1 = *(const f32x4*)(pr_ + 544); \
        f32x4 s2 = *(const f32x4*)(pr_ + 1088); \
        f32x4 s3 = *(const f32x4*)(pr_ + 1632); \
        f32x4 sm = (s0 + s1) + (s2 + s3); \
        u32x4 ow; \
        _Pragma("unroll") \
        for (int r = 0; r < 4; r++) { \
            float v = sm[r] + to_f32(PVUSE[r]); \
            v = v >= 0.f ? v : 0.01f * v; \
            ow[r] = ((unsigned)f2bf(v) << 16) | (tagS + 1u); \
        } \
        char* sp = hn32 + sp_off; \
        if (!gmode) { \
            asm volatile("global_store_dwordx4 %0, %1, off sc0" \
                         :: "v"(sp), "v"(ow) : "memory"); \
        } else { \
            asm volatile("global_store_dwordx4 %0, %1, off sc0 sc1" \
                         :: "v"(sp), "v"(ow) : "memory"); \
        } \
        lastow = ow; lastsp = sp; \
    } \
  } while (0)

template<typename PreT>
__global__ __launch_bounds__(256, 1)
void rnn_scan19(const unsigned short* __restrict__ WbotT,
                const PreT* __restrict__ pre,      // [T][B][H] t-major
                unsigned* __restrict__ hbuf32,     // [2][exchange layout] tagged u32
                unsigned* __restrict__ dflag)      // distress flag + scratch
{
    using p4_t = typename pre4<PreT>::t;
    __shared__ unsigned short Ws[64 * 1024];      // 128KiB, XOR-swizzled rows
    __shared__ float pbuf[2 * 2176];              // 17.4KB double-buffered partials
    const int tid = threadIdx.x, lane = tid & 63, w = tid >> 6;
    const int rg = (int)blockIdx.x & 7;           // &7 -> same rg = same XCD (round-robin)
    const int cs = (int)blockIdx.x >> 3;
    const int n0 = cs * 64;

    // fill Ws swizzled: byte(r,kb) = r*2048 + (kb ^ ((r&7)<<4))
    for (int idx = tid; idx < 64 * 128; idx += 256) {
        int r = idx >> 7, kb = (idx & 127) * 16;
        s16x8 v = *(const s16x8*)(WbotT + (size_t)(n0 + r) * H_ + (idx & 127) * 8);
        *(s16x8*)((char*)Ws + r * 2048 + (kb ^ ((r & 7) << 4))) = v;
    }
    __syncthreads();

    const int l15 = lane & 15, l4 = lane >> 4;
    const int hrow = rg * 8 + (l15 & 7);          // 8 rows; lanes l15>=8 duplicate
    const int col0 = n0 + w * 16 + l4 * 4;        // 4 consecutive output cols

    // consumer poll base (wave w = k-quarter q): lane -> (a=lane>>4, row=lane&7)
    const int tbA_off = rg * 32768 + w * 8192 + (lane >> 4) * 128 + (lane & 7) * 16;
    // producer store offset for (row=l15&7, col0..col0+3)
    const int q_ = col0 >> 8, j_ = (col0 >> 5) & 7, a_ = (col0 >> 3) & 3, p_ = (col0 >> 2) & 1;
    const int sp_off = rg * 32768 + q_ * 8192 + j_ * 1024 + p_ * 512 + (a_ * 8 + (l15 & 7)) * 16;

    // swizzled Ws read bases (unchanged from r15)
    const int b6 = (l15 >> 2) & 1;
    const char* wsRow = (const char*)Ws + l15 * 2048 + ((l4 * 16) ^ ((l15 & 3) << 4)) + w * 512;
    const char* wE = wsRow + b6 * 64;   // even j
    const char* wO = wsRow - b6 * 64;   // odd j

    int slp = 0;                        // adaptive pre-poll sleep (per wave) — r15 tuning
    unsigned gmode = 0;                 // 0 = XCD-local sc0, 1 = L3 sc1 (sticky)
    u32x4 lastow = {};
    char* lastsp = (char*)dflag + 1024 + tid * 16;   // harmless scratch until first store

    p4_t pvA, pvB;
    pvA = pre_ld(pre + (size_t)hrow * H_ + col0);   // pre[t=0]
    asm volatile("s_waitcnt vmcnt(0)" ::: "memory");

    for (int t = 0; t < T_; t += 2) {
        STEP(t,     pvA, pvB);
        STEP(t + 1, pvB, pvA);
    }
}

// ---------- launch ----------
extern "C" void kernel_launch(void* const* d_in, const int* in_sizes, int n_in,
                              void* d_out, int out_size, void* d_ws, size_t ws_size,
                              hipStream_t stream)
{
    const float* x     = (const float*)d_in[0];
    const float* W_in  = (const float*)d_in[1];
    const float* b_in  = (const float*)d_in[2];
    const float* W_h   = (const float*)d_in[3];
    const float* b_h   = (const float*)d_in[4];
    const float* W_out = (const float*)d_in[5];
    const float* b_out = (const float*)d_in[6];
    float* out = (float*)d_out;

    char* ws = (char*)d_ws;
    size_t off = 0;
    auto alloc = [&](size_t bytes) { void* p = ws + off; off += (bytes + 255) & ~(size_t)255; return p; };

    unsigned short* Xb    = (unsigned short*)alloc((size_t)MT_ * I_ * 2);
    unsigned short* WinT  = (unsigned short*)alloc((size_t)H_ * I_ * 2);
    unsigned short* WtopT = (unsigned short*)alloc((size_t)H_ * H_ * 2);
    unsigned short* WbotT = (unsigned short*)alloc((size_t)H_ * H_ * 2);
    unsigned short* WoutT = (unsigned short*)alloc((size_t)O_ * H_ * 2);
    unsigned short* Abuf  = (unsigned short*)alloc((size_t)MT_ * H_ * 2);
    unsigned*       hbuf32 = (unsigned*)alloc((size_t)2 * B_ * H_ * 4);   // tagged ping-pong
    unsigned*       dbuf  = (unsigned*)alloc(8192);                       // distress + scratch
    unsigned short* hfin  = (unsigned short*)alloc((size_t)B_ * H_ * 2);  // unscrambled h_T
    void* pre = ws + off;
    const bool pre_f32 = (off + (size_t)MT_ * H_ * 4) <= ws_size;

    hipMemsetAsync(hbuf32, 0, (size_t)2 * B_ * H_ * 4, stream);
    hipMemsetAsync(dbuf, 0, 8192, stream);

    cvt_x<<<2048, 256, 0, stream>>>(x, Xb, MT_ * I_);
    dim3 tb(32, 8);
    cvt_t<<<dim3(H_ / 32, I_ / 32), tb, 0, stream>>>(W_in,  WinT,  I_, H_, 0);
    cvt_t<<<dim3(H_ / 32, H_ / 32), tb, 0, stream>>>(W_h,   WtopT, H_, H_, 0);
    cvt_t<<<dim3(H_ / 32, H_ / 32), tb, 0, stream>>>(W_h,   WbotT, H_, H_, H_);
    cvt_t<<<dim3(O_ / 32, H_ / 32), tb, 0, stream>>>(W_out, WoutT, H_, O_, 0);

    // GEMM1: A = lrelu(X @ W_in + b_in)   [MT, H] bf16
    gemm_bf16<unsigned short, true, false>
        <<<dim3(MT_ / 128, H_ / 128), 256, 0, stream>>>(Xb, WinT, b_in, Abuf, MT_, I_, H_);

    // GEMM2: pre = A @ Wtop + b_h   written t-major [T][B][H] with nt stores
    if (pre_f32) {
        gemm_bf16<float, false, true>
            <<<dim3(MT_ / 128, H_ / 128), 256, 0, stream>>>(Abuf, WtopT, b_h, (float*)pre, MT_, H_, H_);
        rnn_scan19<float><<<RG_ * CS_, 256, 0, stream>>>(WbotT, (const float*)pre, hbuf32, dbuf);
    } else {
        gemm_bf16<unsigned short, false, true>
            <<<dim3(MT_ / 128, H_ / 128), 256, 0, stream>>>(Abuf, WtopT, b_h, (unsigned short*)pre, MT_, H_, H_);
        rnn_scan19<unsigned short><<<RG_ * CS_, 256, 0, stream>>>(WbotT, (const unsigned short*)pre, hbuf32, dbuf);
    }

    // h_T in slot 0 (tag 1024); unscramble (end-of-dispatch flush makes it coherent)
    strip_h<<<64, 256, 0, stream>>>(hbuf32, hfin);
    gemm_bf16<float, false, false>
        <<<dim3(1, O_ / 128), 256, 0, stream>>>(hfin, WoutT, b_out, out, B_, H_, O_);
}

// Round 20
// 2744.415 us; speedup vs baseline: 1.8184x; 1.0475x over previous
//
#include <hip/hip_runtime.h>
#include <hip/hip_bf16.h>

// ---------- types ----------
typedef __attribute__((ext_vector_type(8))) short  s16x8;
typedef __attribute__((ext_vector_type(4))) float  f32x4;
typedef __attribute__((ext_vector_type(4))) unsigned short u16x4;
typedef __attribute__((ext_vector_type(4))) unsigned int   u32x4;

#define B_  64
#define T_  1024
#define I_  512
#define H_  1024
#define O_  512
#define MT_ 65536   // B_*T_
#define G2_ 4096    // GEMM2 blocks in fused kernel

// scan decomposition: 8 row-groups x 16 col-slices (blocks 0..127 of fused kernel)
#define RG_   8
#define CS_   16

// ---------- helpers ----------
__device__ __forceinline__ unsigned short f2bf(float f) {
    unsigned u = __builtin_bit_cast(unsigned, f);
    u += 0x7FFFu + ((u >> 16) & 1u);
    return (unsigned short)(u >> 16);
}
__device__ __forceinline__ float bf2f(unsigned short h) {
    return __builtin_bit_cast(float, ((unsigned)h) << 16);
}
__device__ __forceinline__ void store_out(float* p, float v) { *p = v; }
__device__ __forceinline__ void store_out(unsigned short* p, float v) { *p = f2bf(v); }

#define GL2LDS16(gp, lp) __builtin_amdgcn_global_load_lds( \
    (const __attribute__((address_space(1))) void*)(gp),   \
    (__attribute__((address_space(3))) void*)(lp), 16, 0, 0)

// ---------- conversion kernels ----------
__global__ void cvt_x(const float* __restrict__ src, unsigned short* __restrict__ dst, int n) {
    int stride = gridDim.x * blockDim.x * 4;
    for (int i = (blockIdx.x * blockDim.x + threadIdx.x) * 4; i < n; i += stride) {
        const float4 v = *(const float4*)(src + i);
        u16x4 o;
        o.x = f2bf(v.x); o.y = f2bf(v.y); o.z = f2bf(v.z); o.w = f2bf(v.w);
        *(u16x4*)(dst + i) = o;
    }
}

// dst[c][r] = bf16(src[row_off + r][c])
__global__ void cvt_t(const float* __restrict__ src, unsigned short* __restrict__ dst,
                      int SR, int SC, int row_off) {
    __shared__ unsigned short tile[32][33];
    int c0 = blockIdx.x * 32, r0 = blockIdx.y * 32;
    int tx = threadIdx.x, ty = threadIdx.y;
    #pragma unroll
    for (int i = 0; i < 32; i += 8)
        tile[ty + i][tx] = f2bf(src[(size_t)(row_off + r0 + ty + i) * SC + c0 + tx]);
    __syncthreads();
    #pragma unroll
    for (int i = 0; i < 32; i += 8)
        dst[(size_t)(c0 + ty + i) * SR + r0 + tx] = tile[tx][ty + i];
}

// unscramble exchange layout (slot 0) -> row-major bf16 h_T.
__global__ void strip_h(const unsigned* __restrict__ src, unsigned short* __restrict__ dst) {
    int idx = blockIdx.x * blockDim.x + threadIdx.x;   // 16384 chunks
    u32x4 v = *(const u32x4*)(src + idx * 4);
    int rg = idx >> 11, c2 = idx & 2047;
    int q = c2 >> 9, c3 = c2 & 511;
    int j = c3 >> 6, c = c3 & 63;
    int p = c >> 5, a = (c >> 3) & 3, row = c & 7;
    int grow = rg * 8 + row;
    int col = q * 256 + j * 32 + a * 8 + p * 4;
    u16x4 o;
    o.x = (unsigned short)(v.x >> 16); o.y = (unsigned short)(v.y >> 16);
    o.z = (unsigned short)(v.z >> 16); o.w = (unsigned short)(v.w >> 16);
    *(u16x4*)(dst + (size_t)grow * H_ + col) = o;
}

// ---------- generic bf16 MFMA GEMM: C[M,N] = act(A[M,K] @ BT[N,K]^T + bias) ----------
template<typename OutT, bool LRELU>
__global__ __launch_bounds__(256)
void gemm_bf16(const unsigned short* __restrict__ A,
               const unsigned short* __restrict__ BT,
               const float* __restrict__ bias,
               OutT* __restrict__ C, int M, int K, int N)
{
    __shared__ unsigned short As[4096]; // [128][32]
    __shared__ unsigned short Bs[4096]; // [128][32]
    const int tid = threadIdx.x, lane = tid & 63, wid = tid >> 6;
    const int wr = wid >> 1, wc = wid & 1;
    const int m0 = blockIdx.x * 128, n0 = blockIdx.y * 128;

    f32x4 acc[4][4] = {};

    const int c = wid * 2;
    const int srow = lane >> 2;
    const int scol = (lane & 3) * 8;
    const unsigned short* Ag0 = A  + (size_t)(m0 + c * 16 + srow) * K + scol;
    const unsigned short* Ag1 = A  + (size_t)(m0 + c * 16 + 16 + srow) * K + scol;
    const unsigned short* Bg0 = BT + (size_t)(n0 + c * 16 + srow) * K + scol;
    const unsigned short* Bg1 = BT + (size_t)(n0 + c * 16 + 16 + srow) * K + scol;

    for (int k0 = 0; k0 < K; k0 += 32) {
        __syncthreads();
        GL2LDS16(Ag0 + k0, As + c * 512);
        GL2LDS16(Ag1 + k0, As + (c + 1) * 512);
        GL2LDS16(Bg0 + k0, Bs + c * 512);
        GL2LDS16(Bg1 + k0, Bs + (c + 1) * 512);
        __syncthreads();

        s16x8 af[4], bfr[4];
        #pragma unroll
        for (int i = 0; i < 4; i++)
            af[i] = *(const s16x8*)(As + (wr * 64 + i * 16 + (lane & 15)) * 32 + (lane >> 4) * 8);
        #pragma unroll
        for (int j = 0; j < 4; j++)
            bfr[j] = *(const s16x8*)(Bs + (wc * 64 + j * 16 + (lane & 15)) * 32 + (lane >> 4) * 8);
        #pragma unroll
        for (int i = 0; i < 4; i++)
            #pragma unroll
            for (int j = 0; j < 4; j++)
                acc[i][j] = __builtin_amdgcn_mfma_f32_16x16x32_bf16(af[i], bfr[j], acc[i][j], 0, 0, 0);
    }

    #pragma unroll
    for (int j = 0; j < 4; j++) {
        const int n = n0 + wc * 64 + j * 16 + (lane & 15);
        const float bv = bias[n];
        #pragma unroll
        for (int i = 0; i < 4; i++) {
            #pragma unroll
            for (int r = 0; r < 4; r++) {
                const int m = m0 + wr * 64 + i * 16 + (lane >> 4) * 4 + r;
                if (m < M) {
                    float v = acc[i][j][r] + bv;
                    if (LRELU) v = v >= 0.f ? v : 0.01f * v;
                    store_out(&C[(size_t)m * N + n], v);
                }
            }
        }
    }
}

// ---------- fused GEMM2 + scan ----------
// Blocks 0..127: r19 scan (XCD-local sc0 tagged exchange, adaptive pacing, single
// barrier), consuming pre[t] as TAGGED u32 = (bf16<<16)|1, validated at use.
// Blocks 128..4223: GEMM2 tiles in T-CHUNK-MAJOR order (all b,n for t<128 first),
// writing tagged pre with sc0 sc1. Scan stalls (rare, early) self-resolve; GEMM2
// blocks depend on nothing -> always retire -> no deadlock.

#define TAGLD2(d, BASE, OFFSTR, SC) asm volatile( \
    "global_load_dwordx4 %0, %1, off offset:" OFFSTR " " SC \
    : "=v"(d) : "v"(BASE))

#define POLLBODY(SC) do { \
    TAGLD2(tv[0],  tA, "0",   SC); TAGLD2(tv[1],  tA, "512",  SC); \
    TAGLD2(tv[2],  tA, "1024",SC); TAGLD2(tv[3],  tA, "1536", SC); \
    TAGLD2(tv[4],  tA, "2048",SC); TAGLD2(tv[5],  tA, "2560", SC); \
    TAGLD2(tv[6],  tA, "3072",SC); TAGLD2(tv[7],  tA, "3584", SC); \
    TAGLD2(tv[8],  tB, "0",   SC); TAGLD2(tv[9],  tB, "512",  SC); \
    TAGLD2(tv[10], tB, "1024",SC); TAGLD2(tv[11], tB, "1536", SC); \
    TAGLD2(tv[12], tB, "2048",SC); TAGLD2(tv[13], tB, "2560", SC); \
    TAGLD2(tv[14], tB, "3072",SC); TAGLD2(tv[15], tB, "3584", SC); \
    } while (0)

// validate tagged pre regs (tag==1) for step S; spin-reload if GEMM2 hasn't landed
#define VALPRE(PV, S) do { \
    unsigned tk = (unsigned)(((PV.x & 0xFFFFu) == 1u) & ((PV.y & 0xFFFFu) == 1u) & \
                             ((PV.z & 0xFFFFu) == 1u) & ((PV.w & 0xFFFFu) == 1u)); \
    while (!__all((int)tk)) { \
        if (!tk) { \
            const unsigned* pp_ = pre32 + ((size_t)(S) * B_ + hrow) * H_ + col0; \
            asm volatile("global_load_dwordx4 %0, %1, off sc0 sc1\n\t" \
                         "s_waitcnt vmcnt(0)" : "=v"(PV) : "v"(pp_) : "memory"); \
            tk = (unsigned)(((PV.x & 0xFFFFu) == 1u) & ((PV.y & 0xFFFFu) == 1u) & \
                            ((PV.z & 0xFFFFu) == 1u) & ((PV.w & 0xFFFFu) == 1u)); \
        } \
        __builtin_amdgcn_s_sleep(2); \
    } } while (0)

#define STEP(S, PVUSE, PVFILL) do { \
    const char* hc32 = (const char*)hbuf32 + (((S) & 1) << 18); \
    char*       hn32 = (char*)hbuf32 + ((((S) + 1) & 1) << 18); \
    const unsigned tagS = (unsigned)(S); \
    const char* tA = hc32 + tbA_off; \
    const char* tB = tA + 4096; \
    float* pb = pbuf + ((S) & 1) * 2176; \
    for (int i_ = 0; i_ < slp; ++i_) __builtin_amdgcn_s_sleep(2); \
    u32x4 tv[16]; \
    unsigned ok = 0u; \
    int rounds_ = 0; \
    for (;;) { \
        if (!ok) { \
            if (!gmode) { POLLBODY("sc0"); } else { POLLBODY("sc0 sc1"); } \
            asm volatile("s_waitcnt vmcnt(0)" ::: "memory"); \
            __builtin_amdgcn_sched_barrier(0); \
            unsigned d_ = 0; \
            _Pragma("unroll") \
            for (int i = 0; i < 16; i++) \
                d_ |= (tv[i].x ^ tagS) | (tv[i].y ^ tagS) | (tv[i].z ^ tagS) | (tv[i].w ^ tagS); \
            ok = ((d_ & 0xFFFFu) == 0u) ? 1u : 0u; \
        } \
        ++rounds_; \
        if (__all((int)ok)) break; \
        if ((rounds_ & 15) == 0) { \
            unsigned fl; \
            asm volatile("global_load_dword %0, %1, off sc0 sc1\n\t" \
                         "s_waitcnt vmcnt(0)" : "=v"(fl) : "v"(dflag) : "memory"); \
            bool anyfl = __any((int)(fl != 0u)); \
            if (!gmode && (anyfl || rounds_ > 96)) { \
                if (!anyfl && lane == 0) { \
                    unsigned one_ = 1u; \
                    asm volatile("global_store_dword %0, %1, off sc0 sc1" \
                                 :: "v"(dflag), "v"(one_) : "memory"); \
                } \
                gmode = 1u; \
                asm volatile("global_store_dwordx4 %0, %1, off sc0 sc1" \
                             :: "v"(lastsp), "v"(lastow) : "memory"); \
            } \
        } \
        __builtin_amdgcn_s_sleep(1); \
    } \
    slp = (rounds_ > 1) ? (slp + 4 > 24 ? 24 : slp + 4) : (slp > 0 ? slp - 1 : 0); \
    { const int sn = ((S) + 1 < T_) ? (S) + 1 : (S); \
      const unsigned* pp_ = pre32 + ((size_t)sn * B_ + hrow) * H_ + col0; \
      asm volatile("global_load_dwordx4 %0, %1, off sc0 sc1" : "=v"(PVFILL) : "v"(pp_)); } \
    f32x4 ac[4] = {}; \
    _Pragma("unroll") \
    for (int cg = 0; cg < 4; ++cg) { \
        const char* pE = wE + cg * 32768; \
        const char* pO = wO + cg * 32768; \
        _Pragma("unroll") \
        for (int j = 0; j < 8; ++j) { \
            u32x4 a2_ = tv[2 * j], b2_ = tv[2 * j + 1]; \
            u32x4 f_; \
            f_.x = (a2_.x >> 16) | (a2_.y & 0xFFFF0000u); \
            f_.y = (a2_.z >> 16) | (a2_.w & 0xFFFF0000u); \
            f_.z = (b2_.x >> 16) | (b2_.y & 0xFFFF0000u); \
            f_.w = (b2_.z >> 16) | (b2_.w & 0xFFFF0000u); \
            s16x8 hfrag = __builtin_bit_cast(s16x8, f_); \
            s16x8 g = *(const s16x8*)(((j & 1) ? pO : pE) + j * 64); \
            ac[cg] = __builtin_amdgcn_mfma_f32_16x16x32_bf16(g, hfrag, ac[cg], 0, 0, 0); \
        } \
    } \
    if (l15 < 8) { \
        float* pw_ = pb + (w * 8 + l15) * 68 + l4 * 4; \
        *(f32x4*)(pw_ +  0) = ac[0]; \
        *(f32x4*)(pw_ + 16) = ac[1]; \
        *(f32x4*)(pw_ + 32) = ac[2]; \
        *(f32x4*)(pw_ + 48) = ac[3]; \
    } \
    asm volatile("s_waitcnt lgkmcnt(0)" ::: "memory"); \
    __builtin_amdgcn_s_barrier(); \
    asm volatile("" ::: "memory"); \
    VALPRE(PVUSE, S); \
    if (l15 < 8) { \
        const float* pr_ = pb + l15 * 68 + w * 16 + l4 * 4; \
        f32x4 s0 = *(const f32x4*)(pr_); \
        f32x4 s1 = *(const f32x4*)(pr_ + 544); \
        f32x4 s2 = *(const f32x4*)(pr_ + 1088); \
        f32x4 s3 = *(const f32x4*)(pr_ + 1632); \
        f32x4 sm = (s0 + s1) + (s2 + s3); \
        u32x4 ow; \
        _Pragma("unroll") \
        for (int r = 0; r < 4; r++) { \
            float v = sm[r] + bf2f((unsigned short)(PVUSE[r] >> 16)); \
            v = v >= 0.f ? v : 0.01f * v; \
            ow[r] = ((unsigned)f2bf(v) << 16) | (tagS + 1u); \
        } \
        char* sp = hn32 + sp_off; \
        if (!gmode) { \
            asm volatile("global_store_dwordx4 %0, %1, off sc0" \
                         :: "v"(sp), "v"(ow) : "memory"); \
        } else { \
            asm volatile("global_store_dwordx4 %0, %1, off sc0 sc1" \
                         :: "v"(sp), "v"(ow) : "memory"); \
        } \
        lastow = ow; lastsp = sp; \
    } \
  } while (0)

__global__ __launch_bounds__(256, 1)
void gemm2_scan(const unsigned short* __restrict__ Abuf,
                const unsigned short* __restrict__ WtopT,
                const float* __restrict__ b_h,
                const unsigned short* __restrict__ WbotT,
                unsigned* __restrict__ pre32,      // [T][B][H] tagged u32
                unsigned* __restrict__ hbuf32,     // [2][exchange layout] tagged u32
                unsigned* __restrict__ dflag)
{
    __shared__ char smem[148480];
    const int bid = (int)blockIdx.x;
    const int tid = threadIdx.x, lane = tid & 63, w = tid >> 6;

    if (bid >= 128) {
        // ================= GEMM2 tile (t-chunk-major order) =================
        unsigned short* As = (unsigned short*)smem;          // [128][32]
        unsigned short* Bs = As + 4096;
        const int g = bid - 128;
        const int tch = g >> 9, b = (g >> 3) & 63, nb = g & 7;
        const int m0 = b * 1024 + tch * 128, n0 = nb * 128;
        const int wr = w >> 1, wc = w & 1;

        f32x4 acc[4][4] = {};
        const int c = w * 2, srow = lane >> 2, scol = (lane & 3) * 8;
        const unsigned short* Ag0 = Abuf  + (size_t)(m0 + c * 16 + srow) * H_ + scol;
        const unsigned short* Ag1 = Abuf  + (size_t)(m0 + c * 16 + 16 + srow) * H_ + scol;
        const unsigned short* Bg0 = WtopT + (size_t)(n0 + c * 16 + srow) * H_ + scol;
        const unsigned short* Bg1 = WtopT + (size_t)(n0 + c * 16 + 16 + srow) * H_ + scol;

        for (int k0 = 0; k0 < H_; k0 += 32) {
            __syncthreads();
            GL2LDS16(Ag0 + k0, As + c * 512);
            GL2LDS16(Ag1 + k0, As + (c + 1) * 512);
            GL2LDS16(Bg0 + k0, Bs + c * 512);
            GL2LDS16(Bg1 + k0, Bs + (c + 1) * 512);
            __syncthreads();

            s16x8 af[4], bfr[4];
            #pragma unroll
            for (int i = 0; i < 4; i++)
                af[i] = *(const s16x8*)(As + (wr * 64 + i * 16 + (lane & 15)) * 32 + (lane >> 4) * 8);
            #pragma unroll
            for (int j = 0; j < 4; j++)
                bfr[j] = *(const s16x8*)(Bs + (wc * 64 + j * 16 + (lane & 15)) * 32 + (lane >> 4) * 8);
            #pragma unroll
            for (int i = 0; i < 4; i++)
                #pragma unroll
                for (int j = 0; j < 4; j++)
                    acc[i][j] = __builtin_amdgcn_mfma_f32_16x16x32_bf16(af[i], bfr[j], acc[i][j], 0, 0, 0);
        }

        #pragma unroll
        for (int j = 0; j < 4; j++) {
            const int n = n0 + wc * 64 + j * 16 + (lane & 15);
            const float bv = b_h[n];
            #pragma unroll
            for (int i = 0; i < 4; i++) {
                #pragma unroll
                for (int r = 0; r < 4; r++) {
                    const int m = m0 + wr * 64 + i * 16 + (lane >> 4) * 4 + r;
                    float v = acc[i][j][r] + bv;
                    size_t row = (size_t)((m & (T_ - 1)) * B_ + (m >> 10));  // t*64 + b
                    unsigned ow = ((unsigned)f2bf(v) << 16) | 1u;
                    unsigned* p = pre32 + row * H_ + n;
                    asm volatile("global_store_dword %0, %1, off sc0 sc1"
                                 :: "v"(p), "v"(ow) : "memory");
                }
            }
        }
        return;
    }

    // ================= scan (r19 structure, tagged pre) =================
    unsigned short* Ws = (unsigned short*)smem;          // 128 KiB swizzled
    float* pbuf = (float*)(smem + 131072);               // 2x2176 f32
    const int rg = bid & 7;                              // &7 -> same rg = same XCD
    const int cs = bid >> 3;
    const int n0 = cs * 64;

    for (int idx = tid; idx < 64 * 128; idx += 256) {
        int r = idx >> 7, kb = (idx & 127) * 16;
        s16x8 v = *(const s16x8*)(WbotT + (size_t)(n0 + r) * H_ + (idx & 127) * 8);
        *(s16x8*)((char*)Ws + r * 2048 + (kb ^ ((r & 7) << 4))) = v;
    }
    __syncthreads();

    const int l15 = lane & 15, l4 = lane >> 4;
    const int hrow = rg * 8 + (l15 & 7);
    const int col0 = n0 + w * 16 + l4 * 4;

    const int tbA_off = rg * 32768 + w * 8192 + (lane >> 4) * 128 + (lane & 7) * 16;
    const int q_ = col0 >> 8, j_ = (col0 >> 5) & 7, a_ = (col0 >> 3) & 3, p_ = (col0 >> 2) & 1;
    const int sp_off = rg * 32768 + q_ * 8192 + j_ * 1024 + p_ * 512 + (a_ * 8 + (l15 & 7)) * 16;

    const int b6 = (l15 >> 2) & 1;
    const char* wsRow = (const char*)Ws + l15 * 2048 + ((l4 * 16) ^ ((l15 & 3) << 4)) + w * 512;
    const char* wE = wsRow + b6 * 64;
    const char* wO = wsRow - b6 * 64;

    int slp = 0;
    unsigned gmode = 0;
    u32x4 lastow = {};
    char* lastsp = (char*)dflag + 1024 + tid * 16;

    u32x4 pvA, pvB;
    {   const unsigned* pp_ = pre32 + (size_t)hrow * H_ + col0;   // pre[t=0]
        asm volatile("global_load_dwordx4 %0, %1, off sc0 sc1" : "=v"(pvA) : "v"(pp_));
        asm volatile("s_waitcnt vmcnt(0)" ::: "memory"); }

    for (int t = 0; t < T_; t += 2) {
        STEP(t,     pvA, pvB);
        STEP(t + 1, pvB, pvA);
    }
}

// ---------- launch ----------
extern "C" void kernel_launch(void* const* d_in, const int* in_sizes, int n_in,
                              void* d_out, int out_size, void* d_ws, size_t ws_size,
                              hipStream_t stream)
{
    const float* x     = (const float*)d_in[0];
    const float* W_in  = (const float*)d_in[1];
    const float* b_in  = (const float*)d_in[2];
    const float* W_h   = (const float*)d_in[3];
    const float* b_h   = (const float*)d_in[4];
    const float* W_out = (const float*)d_in[5];
    const float* b_out = (const float*)d_in[6];
    float* out = (float*)d_out;

    char* ws = (char*)d_ws;
    size_t off = 0;
    auto alloc = [&](size_t bytes) { void* p = ws + off; off += (bytes + 255) & ~(size_t)255; return p; };

    unsigned short* Xb    = (unsigned short*)alloc((size_t)MT_ * I_ * 2);
    unsigned short* WinT  = (unsigned short*)alloc((size_t)H_ * I_ * 2);
    unsigned short* WtopT = (unsigned short*)alloc((size_t)H_ * H_ * 2);
    unsigned short* WbotT = (unsigned short*)alloc((size_t)H_ * H_ * 2);
    unsigned short* WoutT = (unsigned short*)alloc((size_t)O_ * H_ * 2);
    unsigned short* Abuf  = (unsigned short*)alloc((size_t)MT_ * H_ * 2);
    unsigned*       hbuf32 = (unsigned*)alloc((size_t)2 * B_ * H_ * 4);
    unsigned*       dbuf  = (unsigned*)alloc(8192);
    unsigned short* hfin  = (unsigned short*)alloc((size_t)B_ * H_ * 2);
    unsigned*       pre32 = (unsigned*)alloc((size_t)MT_ * H_ * 4);   // tagged pre

    hipMemsetAsync(hbuf32, 0, (size_t)2 * B_ * H_ * 4, stream);
    hipMemsetAsync(dbuf, 0, 8192, stream);
    hipMemsetAsync(pre32, 0, (size_t)MT_ * H_ * 4, stream);   // tag 0 = invalid

    cvt_x<<<2048, 256, 0, stream>>>(x, Xb, MT_ * I_);
    dim3 tb(32, 8);
    cvt_t<<<dim3(H_ / 32, I_ / 32), tb, 0, stream>>>(W_in,  WinT,  I_, H_, 0);
    cvt_t<<<dim3(H_ / 32, H_ / 32), tb, 0, stream>>>(W_h,   WtopT, H_, H_, 0);
    cvt_t<<<dim3(H_ / 32, H_ / 32), tb, 0, stream>>>(W_h,   WbotT, H_, H_, H_);
    cvt_t<<<dim3(O_ / 32, H_ / 32), tb, 0, stream>>>(W_out, WoutT, H_, O_, 0);

    // GEMM1: A = lrelu(X @ W_in + b_in)   [MT, H] bf16
    gemm_bf16<unsigned short, true>
        <<<dim3(MT_ / 128, H_ / 128), 256, 0, stream>>>(Xb, WinT, b_in, Abuf, MT_, I_, H_);

    // Fused: GEMM2 (tagged pre, t-chunk-major) + scan (blocks 0..127)
    gemm2_scan<<<128 + G2_, 256, 0, stream>>>(Abuf, WtopT, b_h, WbotT, pre32, hbuf32, dbuf);

    // h_T in slot 0 (tag 1024); unscramble, then final GEMM
    strip_h<<<64, 256, 0, stream>>>(hbuf32, hfin);
    gemm_bf16<float, false>
        <<<dim3(1, O_ / 128), 256, 0, stream>>>(hfin, WoutT, b_out, out, B_, H_, O_);
}

// Round 21
// 2639.052 us; speedup vs baseline: 1.8910x; 1.0399x over previous
//
#include <hip/hip_runtime.h>
#include <hip/hip_bf16.h>

// ---------- types ----------
typedef __attribute__((ext_vector_type(8))) short  s16x8;
typedef __attribute__((ext_vector_type(4))) float  f32x4;
typedef __attribute__((ext_vector_type(4))) unsigned short u16x4;
typedef __attribute__((ext_vector_type(4))) unsigned int   u32x4;

#define B_  64
#define T_  1024
#define I_  512
#define H_  1024
#define O_  512
#define MT_ 65536   // B_*T_
#define G2_ 4096    // GEMM2 blocks in fused kernel

// scan decomposition: 8 row-groups x 16 col-slices (blocks 0..127 of fused kernel)
#define RG_   8
#define CS_   16

// ---------- helpers ----------
__device__ __forceinline__ unsigned short f2bf(float f) {
    unsigned u = __builtin_bit_cast(unsigned, f);
    u += 0x7FFFu + ((u >> 16) & 1u);
    return (unsigned short)(u >> 16);
}
__device__ __forceinline__ float bf2f(unsigned short h) {
    return __builtin_bit_cast(float, ((unsigned)h) << 16);
}
__device__ __forceinline__ void store_out(float* p, float v) { *p = v; }
__device__ __forceinline__ void store_out(unsigned short* p, float v) { *p = f2bf(v); }

#define GL2LDS16(gp, lp) __builtin_amdgcn_global_load_lds( \
    (const __attribute__((address_space(1))) void*)(gp),   \
    (__attribute__((address_space(3))) void*)(lp), 16, 0, 0)

// ---------- conversion kernels ----------
__global__ void cvt_x(const float* __restrict__ src, unsigned short* __restrict__ dst, int n) {
    int stride = gridDim.x * blockDim.x * 4;
    for (int i = (blockIdx.x * blockDim.x + threadIdx.x) * 4; i < n; i += stride) {
        const float4 v = *(const float4*)(src + i);
        u16x4 o;
        o.x = f2bf(v.x); o.y = f2bf(v.y); o.z = f2bf(v.z); o.w = f2bf(v.w);
        *(u16x4*)(dst + i) = o;
    }
}

// dst[c][r] = bf16(src[row_off + r][c])
__global__ void cvt_t(const float* __restrict__ src, unsigned short* __restrict__ dst,
                      int SR, int SC, int row_off) {
    __shared__ unsigned short tile[32][33];
    int c0 = blockIdx.x * 32, r0 = blockIdx.y * 32;
    int tx = threadIdx.x, ty = threadIdx.y;
    #pragma unroll
    for (int i = 0; i < 32; i += 8)
        tile[ty + i][tx] = f2bf(src[(size_t)(row_off + r0 + ty + i) * SC + c0 + tx]);
    __syncthreads();
    #pragma unroll
    for (int i = 0; i < 32; i += 8)
        dst[(size_t)(c0 + ty + i) * SR + r0 + tx] = tile[tx][ty + i];
}

// unscramble exchange layout (slot 0) -> row-major bf16 h_T.
__global__ void strip_h(const unsigned* __restrict__ src, unsigned short* __restrict__ dst) {
    int idx = blockIdx.x * blockDim.x + threadIdx.x;   // 16384 chunks
    u32x4 v = *(const u32x4*)(src + idx * 4);
    int rg = idx >> 11, c2 = idx & 2047;
    int q = c2 >> 9, c3 = c2 & 511;
    int j = c3 >> 6, c = c3 & 63;
    int p = c >> 5, a = (c >> 3) & 3, row = c & 7;
    int grow = rg * 8 + row;
    int col = q * 256 + j * 32 + a * 8 + p * 4;
    u16x4 o;
    o.x = (unsigned short)(v.x >> 16); o.y = (unsigned short)(v.y >> 16);
    o.z = (unsigned short)(v.z >> 16); o.w = (unsigned short)(v.w >> 16);
    *(u16x4*)(dst + (size_t)grow * H_ + col) = o;
}

// ---------- generic bf16 MFMA GEMM ----------
template<typename OutT, bool LRELU>
__global__ __launch_bounds__(256)
void gemm_bf16(const unsigned short* __restrict__ A,
               const unsigned short* __restrict__ BT,
               const float* __restrict__ bias,
               OutT* __restrict__ C, int M, int K, int N)
{
    __shared__ unsigned short As[4096];
    __shared__ unsigned short Bs[4096];
    const int tid = threadIdx.x, lane = tid & 63, wid = tid >> 6;
    const int wr = wid >> 1, wc = wid & 1;
    const int m0 = blockIdx.x * 128, n0 = blockIdx.y * 128;

    f32x4 acc[4][4] = {};

    const int c = wid * 2;
    const int srow = lane >> 2;
    const int scol = (lane & 3) * 8;
    const unsigned short* Ag0 = A  + (size_t)(m0 + c * 16 + srow) * K + scol;
    const unsigned short* Ag1 = A  + (size_t)(m0 + c * 16 + 16 + srow) * K + scol;
    const unsigned short* Bg0 = BT + (size_t)(n0 + c * 16 + srow) * K + scol;
    const unsigned short* Bg1 = BT + (size_t)(n0 + c * 16 + 16 + srow) * K + scol;

    for (int k0 = 0; k0 < K; k0 += 32) {
        __syncthreads();
        GL2LDS16(Ag0 + k0, As + c * 512);
        GL2LDS16(Ag1 + k0, As + (c + 1) * 512);
        GL2LDS16(Bg0 + k0, Bs + c * 512);
        GL2LDS16(Bg1 + k0, Bs + (c + 1) * 512);
        __syncthreads();

        s16x8 af[4], bfr[4];
        #pragma unroll
        for (int i = 0; i < 4; i++)
            af[i] = *(const s16x8*)(As + (wr * 64 + i * 16 + (lane & 15)) * 32 + (lane >> 4) * 8);
        #pragma unroll
        for (int j = 0; j < 4; j++)
            bfr[j] = *(const s16x8*)(Bs + (wc * 64 + j * 16 + (lane & 15)) * 32 + (lane >> 4) * 8);
        #pragma unroll
        for (int i = 0; i < 4; i++)
            #pragma unroll
            for (int j = 0; j < 4; j++)
                acc[i][j] = __builtin_amdgcn_mfma_f32_16x16x32_bf16(af[i], bfr[j], acc[i][j], 0, 0, 0);
    }

    #pragma unroll
    for (int j = 0; j < 4; j++) {
        const int n = n0 + wc * 64 + j * 16 + (lane & 15);
        const float bv = bias[n];
        #pragma unroll
        for (int i = 0; i < 4; i++) {
            #pragma unroll
            for (int r = 0; r < 4; r++) {
                const int m = m0 + wr * 64 + i * 16 + (lane >> 4) * 4 + r;
                if (m < M) {
                    float v = acc[i][j][r] + bv;
                    if (LRELU) v = v >= 0.f ? v : 0.01f * v;
                    store_out(&C[(size_t)m * N + n], v);
                }
            }
        }
    }
}

// ---------- fused GEMM2 + scan ----------
// Blocks 0..127: r19 scan. Blocks 128..4223: GEMM2 (t-chunk-major), writing plain
// bf16 pre (sc0 sc1) + per-(tch, b-octet, nb) completion counters (agent atomics,
// after vmcnt(0)). Scan gates once per 128 steps on ITS 8 producer tiles only.
// No pre memset needed; counters (in dbuf, zeroed) gate all first reads.

#define TAGLD2(d, BASE, OFFSTR, SC) asm volatile( \
    "global_load_dwordx4 %0, %1, off offset:" OFFSTR " " SC \
    : "=v"(d) : "v"(BASE))

#define POLLBODY(SC) do { \
    TAGLD2(tv[0],  tA, "0",   SC); TAGLD2(tv[1],  tA, "512",  SC); \
    TAGLD2(tv[2],  tA, "1024",SC); TAGLD2(tv[3],  tA, "1536", SC); \
    TAGLD2(tv[4],  tA, "2048",SC); TAGLD2(tv[5],  tA, "2560", SC); \
    TAGLD2(tv[6],  tA, "3072",SC); TAGLD2(tv[7],  tA, "3584", SC); \
    TAGLD2(tv[8],  tB, "0",   SC); TAGLD2(tv[9],  tB, "512",  SC); \
    TAGLD2(tv[10], tB, "1024",SC); TAGLD2(tv[11], tB, "1536", SC); \
    TAGLD2(tv[12], tB, "2048",SC); TAGLD2(tv[13], tB, "2560", SC); \
    TAGLD2(tv[14], tB, "3072",SC); TAGLD2(tv[15], tB, "3584", SC); \
    } while (0)

#define CNTWAIT(CHK) do { \
    const unsigned* cp_ = cnt + (CHK) * 64 + rg * 8 + nbq; \
    unsigned cv_; \
    for (;;) { \
        asm volatile("global_load_dword %0, %1, off sc0 sc1\n\t" \
                     "s_waitcnt vmcnt(0)" : "=v"(cv_) : "v"(cp_) : "memory"); \
        if (cv_ >= 8u) break; \
        __builtin_amdgcn_s_sleep(8); \
    } } while (0)

#define STEP(S, PVUSE, PVFILL) do { \
    const char* hc32 = (const char*)hbuf32 + (((S) & 1) << 18); \
    char*       hn32 = (char*)hbuf32 + ((((S) + 1) & 1) << 18); \
    const unsigned tagS = (unsigned)(S); \
    const char* tA = hc32 + tbA_off; \
    const char* tB = tA + 4096; \
    float* pb = pbuf + ((S) & 1) * 2176; \
    for (int i_ = 0; i_ < slp; ++i_) __builtin_amdgcn_s_sleep(2); \
    u32x4 tv[16]; \
    unsigned ok = 0u; \
    int rounds_ = 0; \
    for (;;) { \
        if (!ok) { \
            if (!gmode) { POLLBODY("sc0"); } else { POLLBODY("sc0 sc1"); } \
            asm volatile("s_waitcnt vmcnt(0)" ::: "memory"); \
            __builtin_amdgcn_sched_barrier(0); \
            unsigned d_ = 0; \
            _Pragma("unroll") \
            for (int i = 0; i < 16; i++) \
                d_ |= (tv[i].x ^ tagS) | (tv[i].y ^ tagS) | (tv[i].z ^ tagS) | (tv[i].w ^ tagS); \
            ok = ((d_ & 0xFFFFu) == 0u) ? 1u : 0u; \
        } \
        ++rounds_; \
        if (__all((int)ok)) break; \
        if ((rounds_ & 15) == 0) { \
            unsigned fl; \
            asm volatile("global_load_dword %0, %1, off sc0 sc1\n\t" \
                         "s_waitcnt vmcnt(0)" : "=v"(fl) : "v"(dflag) : "memory"); \
            bool anyfl = __any((int)(fl != 0u)); \
            if (!gmode && (anyfl || rounds_ > 96)) { \
                if (!anyfl && lane == 0) { \
                    unsigned one_ = 1u; \
                    asm volatile("global_store_dword %0, %1, off sc0 sc1" \
                                 :: "v"(dflag), "v"(one_) : "memory"); \
                } \
                gmode = 1u; \
                asm volatile("global_store_dwordx4 %0, %1, off sc0 sc1" \
                             :: "v"(lastsp), "v"(lastow) : "memory"); \
            } \
        } \
        __builtin_amdgcn_s_sleep(1); \
    } \
    slp = (rounds_ > 1) ? (slp + 4 > 24 ? 24 : slp + 4) : (slp > 0 ? slp - 1 : 0); \
    { const int sn_ = ((S) + 1 < T_) ? (S) + 1 : (S); \
      if (((sn_ & 127) == 0) && ((S) + 1 < T_)) CNTWAIT(sn_ >> 7); \
      const unsigned short* pp_ = preb + ((size_t)sn_ * B_ + hrow) * H_ + col0; \
      asm volatile("global_load_dwordx2 %0, %1, off sc0 sc1" : "=v"(PVFILL) : "v"(pp_)); } \
    f32x4 ac[4] = {}; \
    _Pragma("unroll") \
    for (int cg = 0; cg < 4; ++cg) { \
        const char* pE = wE + cg * 32768; \
        const char* pO = wO + cg * 32768; \
        _Pragma("unroll") \
        for (int j = 0; j < 8; ++j) { \
            u32x4 a2_ = tv[2 * j], b2_ = tv[2 * j + 1]; \
            u32x4 f_; \
            f_.x = (a2_.x >> 16) | (a2_.y & 0xFFFF0000u); \
            f_.y = (a2_.z >> 16) | (a2_.w & 0xFFFF0000u); \
            f_.z = (b2_.x >> 16) | (b2_.y & 0xFFFF0000u); \
            f_.w = (b2_.z >> 16) | (b2_.w & 0xFFFF0000u); \
            s16x8 hfrag = __builtin_bit_cast(s16x8, f_); \
            s16x8 g = *(const s16x8*)(((j & 1) ? pO : pE) + j * 64); \
            ac[cg] = __builtin_amdgcn_mfma_f32_16x16x32_bf16(g, hfrag, ac[cg], 0, 0, 0); \
        } \
    } \
    if (l15 < 8) { \
        float* pw_ = pb + (w * 8 + l15) * 68 + l4 * 4; \
        *(f32x4*)(pw_ +  0) = ac[0]; \
        *(f32x4*)(pw_ + 16) = ac[1]; \
        *(f32x4*)(pw_ + 32) = ac[2]; \
        *(f32x4*)(pw_ + 48) = ac[3]; \
    } \
    asm volatile("s_waitcnt lgkmcnt(0)" ::: "memory"); \
    __builtin_amdgcn_s_barrier(); \
    asm volatile("" ::: "memory"); \
    if (l15 < 8) { \
        const float* pr_ = pb + l15 * 68 + w * 16 + l4 * 4; \
        f32x4 s0 = *(const f32x4*)(pr_); \
        f32x4 s1 = *(const f32x4*)(pr_ + 544); \
        f32x4 s2 = *(const f32x4*)(pr_ + 1088); \
        f32x4 s3 = *(const f32x4*)(pr_ + 1632); \
        f32x4 sm = (s0 + s1) + (s2 + s3); \
        u32x4 ow; \
        _Pragma("unroll") \
        for (int r = 0; r < 4; r++) { \
            float v = sm[r] + bf2f((unsigned short)PVUSE[r]); \
            v = v >= 0.f ? v : 0.01f * v; \
            ow[r] = ((unsigned)f2bf(v) << 16) | (tagS + 1u); \
        } \
        char* sp = hn32 + sp_off; \
        if (!gmode) { \
            asm volatile("global_store_dwordx4 %0, %1, off sc0" \
                         :: "v"(sp), "v"(ow) : "memory"); \
        } else { \
            asm volatile("global_store_dwordx4 %0, %1, off sc0 sc1" \
                         :: "v"(sp), "v"(ow) : "memory"); \
        } \
        lastow = ow; lastsp = sp; \
    } \
  } while (0)

__global__ __launch_bounds__(256, 1)
void gemm2_scan(const unsigned short* __restrict__ Abuf,
                const unsigned short* __restrict__ WtopT,
                const float* __restrict__ b_h,
                const unsigned short* __restrict__ WbotT,
                unsigned short* __restrict__ preb,  // [T][B][H] bf16
                unsigned* __restrict__ hbuf32,      // [2][exchange layout] tagged u32
                unsigned* __restrict__ dflag)       // [0]=distress, +1344: cnt[8][8][8]
{
    __shared__ char smem[148480];
    const int bid = (int)blockIdx.x;
    const int tid = threadIdx.x, lane = tid & 63, w = tid >> 6;
    unsigned* cnt = dflag + 1344;

    if (bid >= 128) {
        // ================= GEMM2 tile (t-chunk-major order) =================
        unsigned short* As = (unsigned short*)smem;
        unsigned short* Bs = As + 4096;
        const int g = bid - 128;
        const int tch = g >> 9, b = (g >> 3) & 63, nb = g & 7;
        const int m0 = b * 1024 + tch * 128, n0 = nb * 128;
        const int wr = w >> 1, wc = w & 1;

        f32x4 acc[4][4] = {};
        const int c = w * 2, srow = lane >> 2, scol = (lane & 3) * 8;
        const unsigned short* Ag0 = Abuf  + (size_t)(m0 + c * 16 + srow) * H_ + scol;
        const unsigned short* Ag1 = Abuf  + (size_t)(m0 + c * 16 + 16 + srow) * H_ + scol;
        const unsigned short* Bg0 = WtopT + (size_t)(n0 + c * 16 + srow) * H_ + scol;
        const unsigned short* Bg1 = WtopT + (size_t)(n0 + c * 16 + 16 + srow) * H_ + scol;

        for (int k0 = 0; k0 < H_; k0 += 32) {
            __syncthreads();
            GL2LDS16(Ag0 + k0, As + c * 512);
            GL2LDS16(Ag1 + k0, As + (c + 1) * 512);
            GL2LDS16(Bg0 + k0, Bs + c * 512);
            GL2LDS16(Bg1 + k0, Bs + (c + 1) * 512);
            __syncthreads();

            s16x8 af[4], bfr[4];
            #pragma unroll
            for (int i = 0; i < 4; i++)
                af[i] = *(const s16x8*)(As + (wr * 64 + i * 16 + (lane & 15)) * 32 + (lane >> 4) * 8);
            #pragma unroll
            for (int j = 0; j < 4; j++)
                bfr[j] = *(const s16x8*)(Bs + (wc * 64 + j * 16 + (lane & 15)) * 32 + (lane >> 4) * 8);
            #pragma unroll
            for (int i = 0; i < 4; i++)
                #pragma unroll
                for (int j = 0; j < 4; j++)
                    acc[i][j] = __builtin_amdgcn_mfma_f32_16x16x32_bf16(af[i], bfr[j], acc[i][j], 0, 0, 0);
        }

        #pragma unroll
        for (int j = 0; j < 4; j++) {
            const int n = n0 + wc * 64 + j * 16 + (lane & 15);
            const float bv = b_h[n];
            #pragma unroll
            for (int i = 0; i < 4; i++) {
                #pragma unroll
                for (int r = 0; r < 4; r++) {
                    const int m = m0 + wr * 64 + i * 16 + (lane >> 4) * 4 + r;
                    float v = acc[i][j][r] + bv;
                    size_t row = (size_t)((m & (T_ - 1)) * B_ + (m >> 10));  // t*64 + b
                    unsigned short hv = f2bf(v);
                    unsigned short* p = preb + row * H_ + n;
                    asm volatile("global_store_short %0, %1, off sc0 sc1"
                                 :: "v"(p), "v"(hv) : "memory");
                }
            }
        }
        asm volatile("s_waitcnt vmcnt(0)" ::: "memory");
        if (tid == 0)
            __hip_atomic_fetch_add(&cnt[tch * 64 + (b >> 3) * 8 + nb], 1u,
                                   __ATOMIC_RELAXED, __HIP_MEMORY_SCOPE_AGENT);
        return;
    }

    // ================= scan (r19 structure, counter-gated pre) =================
    unsigned short* Ws = (unsigned short*)smem;          // 128 KiB swizzled
    float* pbuf = (float*)(smem + 131072);               // 2x2176 f32
    const int rg = bid & 7;                              // &7 -> same rg = same XCD
    const int cs = bid >> 3;
    const int n0 = cs * 64;
    const int nbq = cs >> 1;                             // this block's pre n-block

    for (int idx = tid; idx < 64 * 128; idx += 256) {
        int r = idx >> 7, kb = (idx & 127) * 16;
        s16x8 v = *(const s16x8*)(WbotT + (size_t)(n0 + r) * H_ + (idx & 127) * 8);
        *(s16x8*)((char*)Ws + r * 2048 + (kb ^ ((r & 7) << 4))) = v;
    }
    __syncthreads();

    const int l15 = lane & 15, l4 = lane >> 4;
    const int hrow = rg * 8 + (l15 & 7);
    const int col0 = n0 + w * 16 + l4 * 4;

    const int tbA_off = rg * 32768 + w * 8192 + (lane >> 4) * 128 + (lane & 7) * 16;
    const int q_ = col0 >> 8, j_ = (col0 >> 5) & 7, a_ = (col0 >> 3) & 3, p_ = (col0 >> 2) & 1;
    const int sp_off = rg * 32768 + q_ * 8192 + j_ * 1024 + p_ * 512 + (a_ * 8 + (l15 & 7)) * 16;

    const int b6 = (l15 >> 2) & 1;
    const char* wsRow = (const char*)Ws + l15 * 2048 + ((l4 * 16) ^ ((l15 & 3) << 4)) + w * 512;
    const char* wE = wsRow + b6 * 64;
    const char* wO = wsRow - b6 * 64;

    int slp = 0;
    unsigned gmode = 0;
    u32x4 lastow = {};
    char* lastsp = (char*)dflag + 1024 + tid * 16;

    u16x4 pvA, pvB;
    {   CNTWAIT(0);                                      // chunk 0 producers done
        const unsigned short* pp_ = preb + (size_t)hrow * H_ + col0;
        asm volatile("global_load_dwordx2 %0, %1, off sc0 sc1" : "=v"(pvA) : "v"(pp_));
        asm volatile("s_waitcnt vmcnt(0)" ::: "memory"); }

    for (int t = 0; t < T_; t += 2) {
        STEP(t,     pvA, pvB);
        STEP(t + 1, pvB, pvA);
    }
}

// ---------- launch ----------
extern "C" void kernel_launch(void* const* d_in, const int* in_sizes, int n_in,
                              void* d_out, int out_size, void* d_ws, size_t ws_size,
                              hipStream_t stream)
{
    const float* x     = (const float*)d_in[0];
    const float* W_in  = (const float*)d_in[1];
    const float* b_in  = (const float*)d_in[2];
    const float* W_h   = (const float*)d_in[3];
    const float* b_h   = (const float*)d_in[4];
    const float* W_out = (const float*)d_in[5];
    const float* b_out = (const float*)d_in[6];
    float* out = (float*)d_out;

    char* ws = (char*)d_ws;
    size_t off = 0;
    auto alloc = [&](size_t bytes) { void* p = ws + off; off += (bytes + 255) & ~(size_t)255; return p; };

    unsigned short* Xb    = (unsigned short*)alloc((size_t)MT_ * I_ * 2);
    unsigned short* WinT  = (unsigned short*)alloc((size_t)H_ * I_ * 2);
    unsigned short* WtopT = (unsigned short*)alloc((size_t)H_ * H_ * 2);
    unsigned short* WbotT = (unsigned short*)alloc((size_t)H_ * H_ * 2);
    unsigned short* WoutT = (unsigned short*)alloc((size_t)O_ * H_ * 2);
    unsigned short* Abuf  = (unsigned short*)alloc((size_t)MT_ * H_ * 2);
    unsigned*       hbuf32 = (unsigned*)alloc((size_t)2 * B_ * H_ * 4);
    unsigned*       dbuf  = (unsigned*)alloc(8192);
    unsigned short* hfin  = (unsigned short*)alloc((size_t)B_ * H_ * 2);
    unsigned short* preb  = (unsigned short*)alloc((size_t)MT_ * H_ * 2);  // bf16 pre

    hipMemsetAsync(hbuf32, 0, (size_t)2 * B_ * H_ * 4, stream);
    hipMemsetAsync(dbuf, 0, 8192, stream);   // distress flag + counters

    cvt_x<<<2048, 256, 0, stream>>>(x, Xb, MT_ * I_);
    dim3 tb(32, 8);
    cvt_t<<<dim3(H_ / 32, I_ / 32), tb, 0, stream>>>(W_in,  WinT,  I_, H_, 0);
    cvt_t<<<dim3(H_ / 32, H_ / 32), tb, 0, stream>>>(W_h,   WtopT, H_, H_, 0);
    cvt_t<<<dim3(H_ / 32, H_ / 32), tb, 0, stream>>>(W_h,   WbotT, H_, H_, H_);
    cvt_t<<<dim3(O_ / 32, H_ / 32), tb, 0, stream>>>(W_out, WoutT, H_, O_, 0);

    // GEMM1: A = lrelu(X @ W_in + b_in)   [MT, H] bf16
    gemm_bf16<unsigned short, true>
        <<<dim3(MT_ / 128, H_ / 128), 256, 0, stream>>>(Xb, WinT, b_in, Abuf, MT_, I_, H_);

    // Fused: GEMM2 (bf16 pre + completion counters) + scan (blocks 0..127)
    gemm2_scan<<<128 + G2_, 256, 0, stream>>>(Abuf, WtopT, b_h, WbotT, preb, hbuf32, dbuf);

    // h_T in slot 0 (tag 1024); unscramble, then final GEMM
    strip_h<<<64, 256, 0, stream>>>(hbuf32, hfin);
    gemm_bf16<float, false>
        <<<dim3(1, O_ / 128), 256, 0, stream>>>(hfin, WoutT, b_out, out, B_, H_, O_);
}